// Round 6
// baseline (914.800 us; speedup 1.0000x reference)
//
#include <hip/hip_runtime.h>

#define TT 1024
#define DD 1024
#define BB 8
#define FF 4096
#define MM (BB * TT)
#define CHL 32                 // WKV chunk length
#define NCH (TT / CHL)         // 32 chunks
#define NCHAN (BB * DD)        // 8192 channels

typedef unsigned short u16;
typedef unsigned int u32;

typedef __attribute__((ext_vector_type(8))) short short8;
typedef __attribute__((ext_vector_type(4))) float floatx4;

__device__ __forceinline__ u16 f2bf(float f) {
  u32 u = __float_as_uint(f);
  u32 r = (u + 0x7fffu + ((u >> 16) & 1u)) >> 16;
  return (u16)r;
}
__device__ __forceinline__ float bf2f(u16 h) { return __uint_as_float(((u32)h) << 16); }
__device__ __forceinline__ float sigmoidf_(float v) { return 1.0f / (1.0f + __expf(-v)); }

// ---------------- merged prologue: ln1mix (blocks 0..8191) + 7 weight transposes ----------------
// transposes: fp32[K,N] -> bf16[N,K]. All independent; one launch fills the machine
// and removes 3 launch boundaries.
__global__ __launch_bounds__(256) void prologue_kernel(
    const float* __restrict__ x, const float* __restrict__ attx,
    const float* __restrict__ g, const float* __restrict__ be,
    const float* __restrict__ mk, const float* __restrict__ mv, const float* __restrict__ mr,
    u16* __restrict__ xk, u16* __restrict__ xv, u16* __restrict__ xr,
    float* __restrict__ xn_last,
    const float* __restrict__ Wk, const float* __restrict__ Wv, const float* __restrict__ Wr,
    const float* __restrict__ Wo, const float* __restrict__ Cr,
    const float* __restrict__ Ck, const float* __restrict__ Cv,
    u16* __restrict__ WT4, u16* __restrict__ CrTd, u16* __restrict__ CkT, u16* __restrict__ CvT) {
  int id = blockIdx.x;
  int tid = threadIdx.x;
  __shared__ float tile[32][33];
  __shared__ float red[4][4];

  if (id < MM) {
    // ---- ln1mix ----
    int row = id;
    int b = row >> 10, t = row & (TT - 1);
    float4 xc = ((const float4*)(x + (size_t)row * DD))[tid];
    float4 xp = (t == 0) ? ((const float4*)(attx + (size_t)b * DD))[tid]
                         : ((const float4*)(x + (size_t)(row - 1) * DD))[tid];
    float sc = xc.x + xc.y + xc.z + xc.w;
    float qc = xc.x * xc.x + xc.y * xc.y + xc.z * xc.z + xc.w * xc.w;
    float sp = xp.x + xp.y + xp.z + xp.w;
    float qp = xp.x * xp.x + xp.y * xp.y + xp.z * xp.z + xp.w * xp.w;
#pragma unroll
    for (int o = 32; o > 0; o >>= 1) {
      sc += __shfl_xor(sc, o); qc += __shfl_xor(qc, o);
      sp += __shfl_xor(sp, o); qp += __shfl_xor(qp, o);
    }
    int lane = tid & 63, wid = tid >> 6;
    if (lane == 0) { red[wid][0] = sc; red[wid][1] = qc; red[wid][2] = sp; red[wid][3] = qp; }
    __syncthreads();
    sc = red[0][0] + red[1][0] + red[2][0] + red[3][0];
    qc = red[0][1] + red[1][1] + red[2][1] + red[3][1];
    sp = red[0][2] + red[1][2] + red[2][2] + red[3][2];
    qp = red[0][3] + red[1][3] + red[2][3] + red[3][3];
    const float inv = 1.0f / (float)DD;
    float muc = sc * inv, varc = qc * inv - muc * muc;
    float rc = rsqrtf(varc + 1e-3f);
    float mup = sp * inv, varp = qp * inv - mup * mup;
    float rp = rsqrtf(varp + 1e-3f);
    float4 gg = ((const float4*)g)[tid];
    float4 bb = ((const float4*)be)[tid];
    float4 k4 = ((const float4*)mk)[tid];
    float4 v4 = ((const float4*)mv)[tid];
    float4 r4 = ((const float4*)mr)[tid];
    float xcv[4] = {xc.x, xc.y, xc.z, xc.w};
    float xpv[4] = {xp.x, xp.y, xp.z, xp.w};
    float gv[4] = {gg.x, gg.y, gg.z, gg.w};
    float bv[4] = {bb.x, bb.y, bb.z, bb.w};
    float kv[4] = {k4.x, k4.y, k4.z, k4.w};
    float vv[4] = {v4.x, v4.y, v4.z, v4.w};
    float rv[4] = {r4.x, r4.y, r4.z, r4.w};
    u16 ok[4], ov[4], orr[4];
    float nc[4];
#pragma unroll
    for (int i = 0; i < 4; i++) {
      nc[i] = (xcv[i] - muc) * rc * gv[i] + bv[i];
      float np = (t == 0) ? xpv[i] : ((xpv[i] - mup) * rp * gv[i] + bv[i]);
      ok[i] = f2bf(nc[i] * kv[i] + np * (1.0f - kv[i]));
      ov[i] = f2bf(nc[i] * vv[i] + np * (1.0f - vv[i]));
      orr[i] = f2bf(nc[i] * rv[i] + np * (1.0f - rv[i]));
    }
    size_t o4 = (size_t)row * (DD / 4) + tid;
    ((ushort4*)xk)[o4] = make_ushort4(ok[0], ok[1], ok[2], ok[3]);
    ((ushort4*)xv)[o4] = make_ushort4(ov[0], ov[1], ov[2], ov[3]);
    ((ushort4*)xr)[o4] = make_ushort4(orr[0], orr[1], orr[2], orr[3]);
    if (t == TT - 1)
      ((float4*)xn_last)[(size_t)b * (DD / 4) + tid] = make_float4(nc[0], nc[1], nc[2], nc[3]);
    return;
  }

  // ---- transposes ----
  id -= MM;
  int tx = tid & 31, ty = tid >> 5;
  const float* in;
  u16* outp;
  int K, N, bx, by;
  if (id < 5120) {
    int z = id >> 10, i = id & 1023;
    const float* s5[5] = {Wk, Wv, Wr, Wo, Cr};
    in = s5[z];
    outp = (z == 4) ? CrTd : WT4 + (size_t)z * 1024 * 1024;
    K = 1024; N = 1024; bx = i & 31; by = i >> 5;
  } else if (id < 9216) {
    int i = id - 5120;
    in = Ck; outp = CkT; K = 1024; N = 4096; bx = i & 127; by = i >> 7;
  } else {
    int i = id - 9216;
    in = Cv; outp = CvT; K = 4096; N = 1024; bx = i & 31; by = i >> 5;
  }
  int n0 = bx * 32, k0 = by * 32;
#pragma unroll
  for (int j = 0; j < 32; j += 8)
    tile[ty + j][tx] = in[(size_t)(k0 + ty + j) * N + (n0 + tx)];
  __syncthreads();
#pragma unroll
  for (int j = 0; j < 32; j += 8)
    outp[(size_t)(n0 + ty + j) * K + (k0 + tx)] = f2bf(tile[tx][ty + j]);
}

// ---------------- LN2 + token shift + 2 mixes -> bf16 ----------------
__global__ void ln2mix_kernel(const float* __restrict__ x1, const float* __restrict__ ffnx,
                              const float* __restrict__ g, const float* __restrict__ be,
                              const float* __restrict__ cmk, const float* __restrict__ cmr,
                              u16* __restrict__ xk2, u16* __restrict__ xr2,
                              float* __restrict__ xn2_last) {
  int row = blockIdx.x, tid = threadIdx.x;
  int b = row >> 10, t = row & (TT - 1);
  float4 xc = ((const float4*)(x1 + (size_t)row * DD))[tid];
  float4 xp = (t == 0) ? ((const float4*)(ffnx + (size_t)b * DD))[tid]
                       : ((const float4*)(x1 + (size_t)(row - 1) * DD))[tid];
  float sc = xc.x + xc.y + xc.z + xc.w;
  float qc = xc.x * xc.x + xc.y * xc.y + xc.z * xc.z + xc.w * xc.w;
  float sp = xp.x + xp.y + xp.z + xp.w;
  float qp = xp.x * xp.x + xp.y * xp.y + xp.z * xp.z + xp.w * xp.w;
#pragma unroll
  for (int o = 32; o > 0; o >>= 1) {
    sc += __shfl_xor(sc, o); qc += __shfl_xor(qc, o);
    sp += __shfl_xor(sp, o); qp += __shfl_xor(qp, o);
  }
  __shared__ float red[4][4];
  int lane = tid & 63, wid = tid >> 6;
  if (lane == 0) { red[wid][0] = sc; red[wid][1] = qc; red[wid][2] = sp; red[wid][3] = qp; }
  __syncthreads();
  sc = red[0][0] + red[1][0] + red[2][0] + red[3][0];
  qc = red[0][1] + red[1][1] + red[2][1] + red[3][1];
  sp = red[0][2] + red[1][2] + red[2][2] + red[3][2];
  qp = red[0][3] + red[1][3] + red[2][3] + red[3][3];
  const float inv = 1.0f / (float)DD;
  float muc = sc * inv, varc = qc * inv - muc * muc;
  float rc = rsqrtf(varc + 1e-3f);
  float mup = sp * inv, varp = qp * inv - mup * mup;
  float rp = rsqrtf(varp + 1e-3f);
  float4 gg = ((const float4*)g)[tid];
  float4 bb = ((const float4*)be)[tid];
  float4 k4 = ((const float4*)cmk)[tid];
  float4 r4 = ((const float4*)cmr)[tid];
  float xcv[4] = {xc.x, xc.y, xc.z, xc.w};
  float xpv[4] = {xp.x, xp.y, xp.z, xp.w};
  float gv[4] = {gg.x, gg.y, gg.z, gg.w};
  float bv[4] = {bb.x, bb.y, bb.z, bb.w};
  float kv[4] = {k4.x, k4.y, k4.z, k4.w};
  float rv[4] = {r4.x, r4.y, r4.z, r4.w};
  u16 ok[4], orr[4];
  float nc[4];
#pragma unroll
  for (int i = 0; i < 4; i++) {
    nc[i] = (xcv[i] - muc) * rc * gv[i] + bv[i];
    float np = (t == 0) ? xpv[i] : ((xpv[i] - mup) * rp * gv[i] + bv[i]);
    ok[i] = f2bf(nc[i] * kv[i] + np * (1.0f - kv[i]));
    orr[i] = f2bf(nc[i] * rv[i] + np * (1.0f - rv[i]));
  }
  size_t o4 = (size_t)row * (DD / 4) + tid;
  ((ushort4*)xk2)[o4] = make_ushort4(ok[0], ok[1], ok[2], ok[3]);
  ((ushort4*)xr2)[o4] = make_ushort4(orr[0], orr[1], orr[2], orr[3]);
  if (t == TT - 1)
    ((float4*)xn2_last)[(size_t)b * (DD / 4) + tid] = make_float4(nc[0], nc[1], nc[2], nc[3]);
}

// ================= chunked WKV scan (k/v in bf16) =================
__global__ void wkv_chunk_sum(const u16* __restrict__ K, const u16* __restrict__ V,
                              const float* __restrict__ decay,
                              float* __restrict__ sa, float* __restrict__ sb,
                              float* __restrict__ ps) {
  int f = blockIdx.x * 256 + threadIdx.x;           // 0 .. NCHAN*NCH-1
  int d = f & (DD - 1);
  int bc = f >> 10;
  int b = bc & (BB - 1);
  int chunk = bc >> 3;
  float w = -__expf(decay[d]);
  const u16* kp = K + ((size_t)(b * TT + chunk * CHL)) * DD + d;
  const u16* vp = V + ((size_t)(b * TT + chunk * CHL)) * DD + d;
  float aa = 0.0f, bb = 0.0f, pp = -1e30f;
#pragma unroll
  for (int j = 0; j < CHL; j++) {
    float kt = bf2f(kp[(size_t)j * DD]);
    float vt = bf2f(vp[(size_t)j * DD]);
    float ww2 = pp + w;
    float p2 = fmaxf(ww2, kt);
    float e1 = __expf(ww2 - p2);
    float e2 = __expf(kt - p2);
    aa = e1 * aa + e2 * vt;
    bb = e1 * bb + e2;
    pp = p2;
  }
  int ch = b * DD + d;
  size_t s = (size_t)chunk * NCHAN + ch;
  sa[s] = aa; sb[s] = bb; ps[s] = pp;
}

__global__ void wkv_chunk_scan(const float* __restrict__ sa, const float* __restrict__ sb,
                               const float* __restrict__ ps, const float* __restrict__ decay,
                               const float* __restrict__ aa0, const float* __restrict__ bb0,
                               const float* __restrict__ pp0,
                               float* __restrict__ pa, float* __restrict__ pb,
                               float* __restrict__ ppx,
                               float* __restrict__ aa_out, float* __restrict__ bb_out,
                               float* __restrict__ pp_out) {
  int ch = blockIdx.x * 256 + threadIdx.x;  // 0..NCHAN-1
  int d = ch & (DD - 1);
  float w = -__expf(decay[d]);
  float wL = (float)CHL * w;
  float aa = aa0[ch], bb = bb0[ch], pp = pp0[ch];
  float lsa[NCH], lsb[NCH], lps[NCH];
#pragma unroll
  for (int j = 0; j < NCH; j++) {
    size_t s = (size_t)j * NCHAN + ch;
    lsa[j] = sa[s]; lsb[j] = sb[s]; lps[j] = ps[s];
  }
#pragma unroll
  for (int j = 0; j < NCH; j++) {
    size_t s = (size_t)j * NCHAN + ch;
    pa[s] = aa; pb[s] = bb; ppx[s] = pp;
    float pw = pp + wL;
    float pn = fmaxf(pw, lps[j]);
    float e1 = __expf(pw - pn);
    float e2 = __expf(lps[j] - pn);
    aa = e1 * aa + e2 * lsa[j];
    bb = e1 * bb + e2 * lsb[j];
    pp = pn;
  }
  aa_out[ch] = aa; bb_out[ch] = bb; pp_out[ch] = pp;
}

__global__ void wkv_chunk_out(const u16* __restrict__ K, const u16* __restrict__ V,
                              const u16* __restrict__ sigr, const float* __restrict__ decay,
                              const float* __restrict__ first,
                              const float* __restrict__ pa, const float* __restrict__ pb,
                              const float* __restrict__ ppx, u16* __restrict__ rm) {
  int f = blockIdx.x * 256 + threadIdx.x;
  int d = f & (DD - 1);
  int bc = f >> 10;
  int b = bc & (BB - 1);
  int chunk = bc >> 3;
  float w = -__expf(decay[d]);
  float u = first[d];
  int ch = b * DD + d;
  size_t s = (size_t)chunk * NCHAN + ch;
  float aa = pa[s], bb = pb[s], pp = ppx[s];
  size_t base = ((size_t)(b * TT + chunk * CHL)) * DD + d;
  const u16* kp = K + base;
  const u16* vp = V + base;
  const u16* rp = sigr + base;
  u16* op = rm + base;
#pragma unroll
  for (int j = 0; j < CHL; j++) {
    float kt = bf2f(kp[(size_t)j * DD]);
    float vt = bf2f(vp[(size_t)j * DD]);
    float ww = u + kt;
    float p = fmaxf(pp, ww);
    float e1 = __expf(pp - p);
    float e2 = __expf(ww - p);
    float wkv = __fdividef(e1 * aa + e2 * vt, e1 * bb + e2);
    op[(size_t)j * DD] = f2bf(bf2f(rp[(size_t)j * DD]) * wkv);
    float ww2 = pp + w;
    float p2 = fmaxf(ww2, kt);
    float e1b = __expf(ww2 - p2);
    float e2b = __expf(kt - p2);
    aa = e1b * aa + e2b * vt;
    bb = e1b * bb + e2b;
    pp = p2;
  }
}

// ---------------- bf16 MFMA GEMM, C = A[M,K] @ B (BT given as [N,K]) ----------------
// BK=64, global_load_lds width-16 staging, row-swizzled LDS (pc=(c+r)&7),
// XCD-slab rasterization (flat&7 -> disjoint 8-m-row slab; n outer, m inner).
// 5 blocks/CU: LDS 5x32KB = 160KB exactly; VGPR cap 2048/20 waves = 102 >= 64.
// MODE 3: C0 fp32 = A0@B + R1
// MODE 4: C0 fp32 = R1 + bf2f(R2) * (A0@B)
// MODE 5: batched QKV via z: A=A0+z*M*K, B=BT0+z*N*K, C=(u16*)C0+z*M*N;
//         z<2 -> bf16(v), z==2 -> sigmoid bf16
// MODE 6: merged FFN: bx<32 -> A0(xk2)@Ck cols, relu^2 bf16 -> C0 (stride 4096);
//         bx>=32 -> A1(xr2)@Cr cols, sigmoid bf16 -> C1 (stride 1024).

template <int MODE>
__launch_bounds__(256, 5)
__global__ void gemm_bt(const u16* __restrict__ A0, const u16* __restrict__ A1,
                        const u16* __restrict__ BT0,
                        const float* R1, const u16* R2,
                        void* C0, void* C1, int M, int N, int K) {
  __shared__ u16 lA[128 * 64];
  __shared__ u16 lB[128 * 64];
  int tid = threadIdx.x;
  int lane = tid & 63;
  int wid = tid >> 6;
  int wy = wid >> 1, wx = wid & 1;

  const u16* A = A0;
  const u16* BT = BT0;
  void* Cout = C0;
  if (MODE == 5) {
    int z = blockIdx.z;
    A = A0 + (size_t)z * M * K;
    BT = BT0 + (size_t)z * N * K;
    Cout = (void*)((u16*)C0 + (size_t)z * M * N);
  }

  // XCD-slab raster: flat&7 = m-slab (requires gridDim.y==64)
  int bx = blockIdx.x, by = blockIdx.y;
  {
    int flat = by * gridDim.x + bx;
    int j = flat >> 3;
    by = (flat & 7) * 8 + (j & 7);
    bx = j >> 3;
  }
  int m0 = by * 128, n0 = bx * 128;

  bool isCr = false;
  if (MODE == 6) {
    isCr = (bx >= 32);
    A = isCr ? A1 : A0;   // Cr columns need the r-mix activations
  }

  int rlo = lane & 15;
  // staging addressing: chunk i = q*256+tid; r=i>>3, pc=i&7, c=(pc-r)&7 (q-indep)
  int rr = tid >> 3;
  int cc = ((tid & 7) - rr) & 7;
  const u16* gA = A + (size_t)(m0 + rr) * K + cc * 8;
  const u16* gB = BT + (size_t)(n0 + rr) * K + cc * 8;
  u16* ldsA = lA + wid * 512;
  u16* ldsB = lB + wid * 512;
  size_t qstep = (size_t)32 * K;

  floatx4 acc[4][4];
#pragma unroll
  for (int mi = 0; mi < 4; mi++)
#pragma unroll
    for (int ni = 0; ni < 4; ni++)
#pragma unroll
      for (int e = 0; e < 4; e++) acc[mi][ni][e] = 0.0f;

  for (int kt = 0; kt < K; kt += 64) {
    __syncthreads();
#pragma unroll
    for (int q = 0; q < 4; q++) {
      __builtin_amdgcn_global_load_lds(gA + q * qstep + kt, ldsA + q * 2048, 16, 0, 0);
      __builtin_amdgcn_global_load_lds(gB + q * qstep + kt, ldsB + q * 2048, 16, 0, 0);
    }
    __syncthreads();
    short8 af[2][4], bfr[2][4];
#pragma unroll
    for (int s = 0; s < 2; s++) {
      int cbase = s * 4 + (lane >> 4);
#pragma unroll
      for (int mi = 0; mi < 4; mi++) {
        int row = wy * 64 + mi * 16 + rlo;
        af[s][mi] = *(const short8*)&lA[row * 64 + (((cbase + row) & 7) << 3)];
      }
#pragma unroll
      for (int ni = 0; ni < 4; ni++) {
        int row = wx * 64 + ni * 16 + rlo;
        bfr[s][ni] = *(const short8*)&lB[row * 64 + (((cbase + row) & 7) << 3)];
      }
    }
#pragma unroll
    for (int s = 0; s < 2; s++)
#pragma unroll
      for (int mi = 0; mi < 4; mi++)
#pragma unroll
        for (int ni = 0; ni < 4; ni++)
          acc[mi][ni] =
              __builtin_amdgcn_mfma_f32_16x16x32_bf16(af[s][mi], bfr[s][ni], acc[mi][ni], 0, 0, 0);
  }

  int rbase = (lane >> 4) * 4;
#pragma unroll
  for (int mi = 0; mi < 4; mi++) {
#pragma unroll
    for (int ni = 0; ni < 4; ni++) {
#pragma unroll
      for (int r = 0; r < 4; r++) {
        int row = m0 + wy * 64 + mi * 16 + rbase + r;
        int col = n0 + wx * 64 + ni * 16 + rlo;
        float v = acc[mi][ni][r];
        if (MODE == 6) {
          if (!isCr) {
            float tpos = fmaxf(v, 0.0f);
            ((u16*)C0)[(size_t)row * 4096 + col] = f2bf(tpos * tpos);
          } else {
            ((u16*)C1)[(size_t)row * 1024 + (col - 4096)] = f2bf(sigmoidf_(v));
          }
        } else {
          size_t idx = (size_t)row * N + col;
          if (MODE == 3) {
            ((float*)Cout)[idx] = v + R1[idx];
          } else if (MODE == 4) {
            ((float*)Cout)[idx] = R1[idx] + bf2f(R2[idx]) * v;
          } else if (MODE == 5) {
            ((u16*)Cout)[idx] = (blockIdx.z == 2) ? f2bf(sigmoidf_(v)) : f2bf(v);
          }
        }
      }
    }
  }
}

extern "C" void kernel_launch(void* const* d_in, const int* in_sizes, int n_in,
                              void* d_out, int out_size, void* d_ws, size_t ws_size,
                              hipStream_t stream) {
  const float* x    = (const float*)d_in[0];
  const float* attx = (const float*)d_in[1];
  const float* aa0  = (const float*)d_in[2];
  const float* bb0  = (const float*)d_in[3];
  const float* pp0  = (const float*)d_in[4];
  const float* ffnx = (const float*)d_in[5];
  const float* ln1g = (const float*)d_in[6];
  const float* ln1b = (const float*)d_in[7];
  const float* ln2g = (const float*)d_in[8];
  const float* ln2b = (const float*)d_in[9];
  const float* mk   = (const float*)d_in[10];
  const float* mv   = (const float*)d_in[11];
  const float* mr   = (const float*)d_in[12];
  const float* decay= (const float*)d_in[13];
  const float* first= (const float*)d_in[14];
  const float* Wk   = (const float*)d_in[15];
  const float* Wv   = (const float*)d_in[16];
  const float* Wr   = (const float*)d_in[17];
  const float* Wo   = (const float*)d_in[18];
  const float* cmk  = (const float*)d_in[19];
  const float* cmr  = (const float*)d_in[20];
  const float* Ck   = (const float*)d_in[21];
  const float* Cr   = (const float*)d_in[22];
  const float* Cv   = (const float*)d_in[23];

  float* out      = (float*)d_out;
  float* xn_last  = out + (size_t)BB * TT * DD;
  float* aa_out   = xn_last + BB * DD;
  float* bb_out   = aa_out + BB * DD;
  float* pp_out   = bb_out + BB * DD;
  float* xn2_last = pp_out + BB * DD;
  float* x1 = out;  // x1 lives in the out buffer

  char* ws = (char*)d_ws;
  const size_t MB = 1024ull * 1024ull;
  u16* WT4   = (u16*)(ws + 0 * MB);     // Wk,Wv,Wr,Wo transposed bf16, 2MB each
  u16* WkT   = WT4;
  u16* WoT   = WT4 + 3u * 1024 * 1024;
  u16* CkCrT = (u16*)(ws + 8 * MB);     // [5120,1024] bf16 = 10MB (Ck rows 0..4095, Cr rows 4096..5119)
  u16* CrTd  = CkCrT + (size_t)4096 * 1024;
  u16* CvT   = (u16*)(ws + 18 * MB);    // 8MB  [1024,4096]
  u16* xk    = (u16*)(ws + 26 * MB);    // 16MB each, contiguous for batched QKV A
  u16* xv    = (u16*)(ws + 42 * MB);
  u16* xr    = (u16*)(ws + 58 * MB);
  u16* kbuf  = (u16*)(ws + 74 * MB);    // 16MB bf16 each, contiguous for batched QKV C
  u16* vbuf  = (u16*)(ws + 90 * MB);
  u16* sigr  = (u16*)(ws + 106 * MB);
  float* sab = (float*)(ws + 122 * MB); // 1MB each
  float* sbb = (float*)(ws + 123 * MB);
  float* psb = (float*)(ws + 124 * MB);
  float* pab = (float*)(ws + 125 * MB);
  float* pbb = (float*)(ws + 126 * MB);
  float* ppb = (float*)(ws + 127 * MB);
  // reuse (lifetimes disjoint):
  u16* rmb   = (u16*)(ws + 26 * MB);    // over xk (dead after QKV GEMM)
  u16* xk2   = (u16*)(ws + 26 * MB);    // over rmb (dead after Wo GEMM)
  u16* xr2   = (u16*)(ws + 42 * MB);    // over xv
  u16* sigr2 = (u16*)(ws + 58 * MB);    // over xr
  u16* kc    = (u16*)(ws + 74 * MB);    // 64MB over kbuf/vbuf/sigr/s* (all dead after chunk_out)

  // merged prologue: ln1mix (8192) + square transposes (5120) + Ck (4096) + Cv (4096)
  prologue_kernel<<<MM + 5120 + 4096 + 4096, 256, 0, stream>>>(
      x, attx, ln1g, ln1b, mk, mv, mr, xk, xv, xr, xn_last,
      Wk, Wv, Wr, Wo, Cr, Ck, Cv, WT4, CrTd, CkCrT, CvT);

  // batched QKV: z=0 -> kbuf (bf16), z=1 -> vbuf (bf16), z=2 -> sigr (sigmoid bf16)
  gemm_bt<5><<<dim3(8, 64, 3), 256, 0, stream>>>(xk, nullptr, WkT, nullptr, nullptr,
                                                 kbuf, nullptr, MM, 1024, 1024);

  wkv_chunk_sum<<<NCHAN * NCH / 256, 256, 0, stream>>>(kbuf, vbuf, decay, sab, sbb, psb);
  wkv_chunk_scan<<<NCHAN / 256, 256, 0, stream>>>(sab, sbb, psb, decay, aa0, bb0, pp0,
                                                  pab, pbb, ppb, aa_out, bb_out, pp_out);
  wkv_chunk_out<<<NCHAN * NCH / 256, 256, 0, stream>>>(kbuf, vbuf, sigr, decay, first,
                                                       pab, pbb, ppb, rmb);

  gemm_bt<3><<<dim3(8, 64), 256, 0, stream>>>(rmb, nullptr, WoT, x, nullptr,
                                              x1, nullptr, MM, 1024, 1024);

  ln2mix_kernel<<<MM, 256, 0, stream>>>(x1, ffnx, ln2g, ln2b, cmk, cmr, xk2, xr2, xn2_last);

  // merged FFN [Ck|Cr]: bx<32 uses xk2 -> kc (relu^2), bx>=32 uses xr2 -> sigr2 (sigmoid)
  gemm_bt<6><<<dim3(40, 64), 256, 0, stream>>>(xk2, xr2, CkCrT, nullptr, nullptr,
                                               kc, sigr2, MM, 5120, 1024);

  gemm_bt<4><<<dim3(8, 64), 256, 0, stream>>>(kc, nullptr, CvT, x1, sigr2,
                                              out, nullptr, MM, 1024, 4096);
}

// Round 7
// 503.804 us; speedup vs baseline: 1.8158x; 1.8158x over previous
//
#include <hip/hip_runtime.h>

#define TT 1024
#define DD 1024
#define BB 8
#define FF 4096
#define MM (BB * TT)
#define CHL 32                 // WKV chunk length
#define NCH (TT / CHL)         // 32 chunks
#define NCHAN (BB * DD)        // 8192 channels

typedef unsigned short u16;
typedef unsigned int u32;

typedef __attribute__((ext_vector_type(8))) short short8;
typedef __attribute__((ext_vector_type(4))) float floatx4;

__device__ __forceinline__ u16 f2bf(float f) {
  u32 u = __float_as_uint(f);
  u32 r = (u + 0x7fffu + ((u >> 16) & 1u)) >> 16;
  return (u16)r;
}
__device__ __forceinline__ float bf2f(u16 h) { return __uint_as_float(((u32)h) << 16); }
__device__ __forceinline__ float sigmoidf_(float v) { return 1.0f / (1.0f + __expf(-v)); }

// ---------------- merged prologue: ln1mix (blocks 0..8191) + 7 weight transposes ----------------
__global__ __launch_bounds__(256) void prologue_kernel(
    const float* __restrict__ x, const float* __restrict__ attx,
    const float* __restrict__ g, const float* __restrict__ be,
    const float* __restrict__ mk, const float* __restrict__ mv, const float* __restrict__ mr,
    u16* __restrict__ xk, u16* __restrict__ xv, u16* __restrict__ xr,
    float* __restrict__ xn_last,
    const float* __restrict__ Wk, const float* __restrict__ Wv, const float* __restrict__ Wr,
    const float* __restrict__ Wo, const float* __restrict__ Cr,
    const float* __restrict__ Ck, const float* __restrict__ Cv,
    u16* __restrict__ WT4, u16* __restrict__ CrTd, u16* __restrict__ CkT, u16* __restrict__ CvT) {
  int id = blockIdx.x;
  int tid = threadIdx.x;
  __shared__ float tile[32][33];
  __shared__ float red[4][4];

  if (id < MM) {
    // ---- ln1mix ----
    int row = id;
    int b = row >> 10, t = row & (TT - 1);
    float4 xc = ((const float4*)(x + (size_t)row * DD))[tid];
    float4 xp = (t == 0) ? ((const float4*)(attx + (size_t)b * DD))[tid]
                         : ((const float4*)(x + (size_t)(row - 1) * DD))[tid];
    float sc = xc.x + xc.y + xc.z + xc.w;
    float qc = xc.x * xc.x + xc.y * xc.y + xc.z * xc.z + xc.w * xc.w;
    float sp = xp.x + xp.y + xp.z + xp.w;
    float qp = xp.x * xp.x + xp.y * xp.y + xp.z * xp.z + xp.w * xp.w;
#pragma unroll
    for (int o = 32; o > 0; o >>= 1) {
      sc += __shfl_xor(sc, o); qc += __shfl_xor(qc, o);
      sp += __shfl_xor(sp, o); qp += __shfl_xor(qp, o);
    }
    int lane = tid & 63, wid = tid >> 6;
    if (lane == 0) { red[wid][0] = sc; red[wid][1] = qc; red[wid][2] = sp; red[wid][3] = qp; }
    __syncthreads();
    sc = red[0][0] + red[1][0] + red[2][0] + red[3][0];
    qc = red[0][1] + red[1][1] + red[2][1] + red[3][1];
    sp = red[0][2] + red[1][2] + red[2][2] + red[3][2];
    qp = red[0][3] + red[1][3] + red[2][3] + red[3][3];
    const float inv = 1.0f / (float)DD;
    float muc = sc * inv, varc = qc * inv - muc * muc;
    float rc = rsqrtf(varc + 1e-3f);
    float mup = sp * inv, varp = qp * inv - mup * mup;
    float rp = rsqrtf(varp + 1e-3f);
    float4 gg = ((const float4*)g)[tid];
    float4 bb = ((const float4*)be)[tid];
    float4 k4 = ((const float4*)mk)[tid];
    float4 v4 = ((const float4*)mv)[tid];
    float4 r4 = ((const float4*)mr)[tid];
    float xcv[4] = {xc.x, xc.y, xc.z, xc.w};
    float xpv[4] = {xp.x, xp.y, xp.z, xp.w};
    float gv[4] = {gg.x, gg.y, gg.z, gg.w};
    float bv[4] = {bb.x, bb.y, bb.z, bb.w};
    float kv[4] = {k4.x, k4.y, k4.z, k4.w};
    float vv[4] = {v4.x, v4.y, v4.z, v4.w};
    float rv[4] = {r4.x, r4.y, r4.z, r4.w};
    u16 ok[4], ov[4], orr[4];
    float nc[4];
#pragma unroll
    for (int i = 0; i < 4; i++) {
      nc[i] = (xcv[i] - muc) * rc * gv[i] + bv[i];
      float np = (t == 0) ? xpv[i] : ((xpv[i] - mup) * rp * gv[i] + bv[i]);
      ok[i] = f2bf(nc[i] * kv[i] + np * (1.0f - kv[i]));
      ov[i] = f2bf(nc[i] * vv[i] + np * (1.0f - vv[i]));
      orr[i] = f2bf(nc[i] * rv[i] + np * (1.0f - rv[i]));
    }
    size_t o4 = (size_t)row * (DD / 4) + tid;
    ((ushort4*)xk)[o4] = make_ushort4(ok[0], ok[1], ok[2], ok[3]);
    ((ushort4*)xv)[o4] = make_ushort4(ov[0], ov[1], ov[2], ov[3]);
    ((ushort4*)xr)[o4] = make_ushort4(orr[0], orr[1], orr[2], orr[3]);
    if (t == TT - 1)
      ((float4*)xn_last)[(size_t)b * (DD / 4) + tid] = make_float4(nc[0], nc[1], nc[2], nc[3]);
    return;
  }

  // ---- transposes ----
  id -= MM;
  int tx = tid & 31, ty = tid >> 5;
  const float* in;
  u16* outp;
  int K, N, bx, by;
  if (id < 5120) {
    int z = id >> 10, i = id & 1023;
    const float* s5[5] = {Wk, Wv, Wr, Wo, Cr};
    in = s5[z];
    outp = (z == 4) ? CrTd : WT4 + (size_t)z * 1024 * 1024;
    K = 1024; N = 1024; bx = i & 31; by = i >> 5;
  } else if (id < 9216) {
    int i = id - 5120;
    in = Ck; outp = CkT; K = 1024; N = 4096; bx = i & 127; by = i >> 7;
  } else {
    int i = id - 9216;
    in = Cv; outp = CvT; K = 4096; N = 1024; bx = i & 31; by = i >> 5;
  }
  int n0 = bx * 32, k0 = by * 32;
#pragma unroll
  for (int j = 0; j < 32; j += 8)
    tile[ty + j][tx] = in[(size_t)(k0 + ty + j) * N + (n0 + tx)];
  __syncthreads();
#pragma unroll
  for (int j = 0; j < 32; j += 8)
    outp[(size_t)(n0 + ty + j) * K + (k0 + tx)] = f2bf(tile[tx][ty + j]);
}

// ---------------- LN2 + token shift + 2 mixes -> bf16 ----------------
__global__ void ln2mix_kernel(const float* __restrict__ x1, const float* __restrict__ ffnx,
                              const float* __restrict__ g, const float* __restrict__ be,
                              const float* __restrict__ cmk, const float* __restrict__ cmr,
                              u16* __restrict__ xk2, u16* __restrict__ xr2,
                              float* __restrict__ xn2_last) {
  int row = blockIdx.x, tid = threadIdx.x;
  int b = row >> 10, t = row & (TT - 1);
  float4 xc = ((const float4*)(x1 + (size_t)row * DD))[tid];
  float4 xp = (t == 0) ? ((const float4*)(ffnx + (size_t)b * DD))[tid]
                       : ((const float4*)(x1 + (size_t)(row - 1) * DD))[tid];
  float sc = xc.x + xc.y + xc.z + xc.w;
  float qc = xc.x * xc.x + xc.y * xc.y + xc.z * xc.z + xc.w * xc.w;
  float sp = xp.x + xp.y + xp.z + xp.w;
  float qp = xp.x * xp.x + xp.y * xp.y + xp.z * xp.z + xp.w * xp.w;
#pragma unroll
  for (int o = 32; o > 0; o >>= 1) {
    sc += __shfl_xor(sc, o); qc += __shfl_xor(qc, o);
    sp += __shfl_xor(sp, o); qp += __shfl_xor(qp, o);
  }
  __shared__ float red[4][4];
  int lane = tid & 63, wid = tid >> 6;
  if (lane == 0) { red[wid][0] = sc; red[wid][1] = qc; red[wid][2] = sp; red[wid][3] = qp; }
  __syncthreads();
  sc = red[0][0] + red[1][0] + red[2][0] + red[3][0];
  qc = red[0][1] + red[1][1] + red[2][1] + red[3][1];
  sp = red[0][2] + red[1][2] + red[2][2] + red[3][2];
  qp = red[0][3] + red[1][3] + red[2][3] + red[3][3];
  const float inv = 1.0f / (float)DD;
  float muc = sc * inv, varc = qc * inv - muc * muc;
  float rc = rsqrtf(varc + 1e-3f);
  float mup = sp * inv, varp = qp * inv - mup * mup;
  float rp = rsqrtf(varp + 1e-3f);
  float4 gg = ((const float4*)g)[tid];
  float4 bb = ((const float4*)be)[tid];
  float4 k4 = ((const float4*)cmk)[tid];
  float4 r4 = ((const float4*)cmr)[tid];
  float xcv[4] = {xc.x, xc.y, xc.z, xc.w};
  float xpv[4] = {xp.x, xp.y, xp.z, xp.w};
  float gv[4] = {gg.x, gg.y, gg.z, gg.w};
  float bv[4] = {bb.x, bb.y, bb.z, bb.w};
  float kv[4] = {k4.x, k4.y, k4.z, k4.w};
  float rv[4] = {r4.x, r4.y, r4.z, r4.w};
  u16 ok[4], orr[4];
  float nc[4];
#pragma unroll
  for (int i = 0; i < 4; i++) {
    nc[i] = (xcv[i] - muc) * rc * gv[i] + bv[i];
    float np = (t == 0) ? xpv[i] : ((xpv[i] - mup) * rp * gv[i] + bv[i]);
    ok[i] = f2bf(nc[i] * kv[i] + np * (1.0f - kv[i]));
    orr[i] = f2bf(nc[i] * rv[i] + np * (1.0f - rv[i]));
  }
  size_t o4 = (size_t)row * (DD / 4) + tid;
  ((ushort4*)xk2)[o4] = make_ushort4(ok[0], ok[1], ok[2], ok[3]);
  ((ushort4*)xr2)[o4] = make_ushort4(orr[0], orr[1], orr[2], orr[3]);
  if (t == TT - 1)
    ((float4*)xn2_last)[(size_t)b * (DD / 4) + tid] = make_float4(nc[0], nc[1], nc[2], nc[3]);
}

// ================= chunked WKV scan (k/v in bf16) =================
__global__ void wkv_chunk_sum(const u16* __restrict__ K, const u16* __restrict__ V,
                              const float* __restrict__ decay,
                              float* __restrict__ sa, float* __restrict__ sb,
                              float* __restrict__ ps) {
  int f = blockIdx.x * 256 + threadIdx.x;           // 0 .. NCHAN*NCH-1
  int d = f & (DD - 1);
  int bc = f >> 10;
  int b = bc & (BB - 1);
  int chunk = bc >> 3;
  float w = -__expf(decay[d]);
  const u16* kp = K + ((size_t)(b * TT + chunk * CHL)) * DD + d;
  const u16* vp = V + ((size_t)(b * TT + chunk * CHL)) * DD + d;
  float aa = 0.0f, bb = 0.0f, pp = -1e30f;
#pragma unroll
  for (int j = 0; j < CHL; j++) {
    float kt = bf2f(kp[(size_t)j * DD]);
    float vt = bf2f(vp[(size_t)j * DD]);
    float ww2 = pp + w;
    float p2 = fmaxf(ww2, kt);
    float e1 = __expf(ww2 - p2);
    float e2 = __expf(kt - p2);
    aa = e1 * aa + e2 * vt;
    bb = e1 * bb + e2;
    pp = p2;
  }
  int ch = b * DD + d;
  size_t s = (size_t)chunk * NCHAN + ch;
  sa[s] = aa; sb[s] = bb; ps[s] = pp;
}

__global__ void wkv_chunk_scan(const float* __restrict__ sa, const float* __restrict__ sb,
                               const float* __restrict__ ps, const float* __restrict__ decay,
                               const float* __restrict__ aa0, const float* __restrict__ bb0,
                               const float* __restrict__ pp0,
                               float* __restrict__ pa, float* __restrict__ pb,
                               float* __restrict__ ppx,
                               float* __restrict__ aa_out, float* __restrict__ bb_out,
                               float* __restrict__ pp_out) {
  int ch = blockIdx.x * 256 + threadIdx.x;  // 0..NCHAN-1
  int d = ch & (DD - 1);
  float w = -__expf(decay[d]);
  float wL = (float)CHL * w;
  float aa = aa0[ch], bb = bb0[ch], pp = pp0[ch];
  float lsa[NCH], lsb[NCH], lps[NCH];
#pragma unroll
  for (int j = 0; j < NCH; j++) {
    size_t s = (size_t)j * NCHAN + ch;
    lsa[j] = sa[s]; lsb[j] = sb[s]; lps[j] = ps[s];
  }
#pragma unroll
  for (int j = 0; j < NCH; j++) {
    size_t s = (size_t)j * NCHAN + ch;
    pa[s] = aa; pb[s] = bb; ppx[s] = pp;
    float pw = pp + wL;
    float pn = fmaxf(pw, lps[j]);
    float e1 = __expf(pw - pn);
    float e2 = __expf(lps[j] - pn);
    aa = e1 * aa + e2 * lsa[j];
    bb = e1 * bb + e2 * lsb[j];
    pp = pn;
  }
  aa_out[ch] = aa; bb_out[ch] = bb; pp_out[ch] = pp;
}

__global__ void wkv_chunk_out(const u16* __restrict__ K, const u16* __restrict__ V,
                              const u16* __restrict__ sigr, const float* __restrict__ decay,
                              const float* __restrict__ first,
                              const float* __restrict__ pa, const float* __restrict__ pb,
                              const float* __restrict__ ppx, u16* __restrict__ rm) {
  int f = blockIdx.x * 256 + threadIdx.x;
  int d = f & (DD - 1);
  int bc = f >> 10;
  int b = bc & (BB - 1);
  int chunk = bc >> 3;
  float w = -__expf(decay[d]);
  float u = first[d];
  int ch = b * DD + d;
  size_t s = (size_t)chunk * NCHAN + ch;
  float aa = pa[s], bb = pb[s], pp = ppx[s];
  size_t base = ((size_t)(b * TT + chunk * CHL)) * DD + d;
  const u16* kp = K + base;
  const u16* vp = V + base;
  const u16* rp = sigr + base;
  u16* op = rm + base;
#pragma unroll
  for (int j = 0; j < CHL; j++) {
    float kt = bf2f(kp[(size_t)j * DD]);
    float vt = bf2f(vp[(size_t)j * DD]);
    float ww = u + kt;
    float p = fmaxf(pp, ww);
    float e1 = __expf(pp - p);
    float e2 = __expf(ww - p);
    float wkv = __fdividef(e1 * aa + e2 * vt, e1 * bb + e2);
    op[(size_t)j * DD] = f2bf(bf2f(rp[(size_t)j * DD]) * wkv);
    float ww2 = pp + w;
    float p2 = fmaxf(ww2, kt);
    float e1b = __expf(ww2 - p2);
    float e2b = __expf(kt - p2);
    aa = e1b * aa + e2b * vt;
    bb = e1b * bb + e2b;
    pp = p2;
  }
}

// ---------------- bf16 MFMA GEMM, C = A[M,K] @ B (BT given as [N,K]) ----------------
// BK=64, global_load_lds width-16 staging, row-swizzled LDS (pc=(c+r)&7),
// XCD-slab rasterization (flat&7 -> disjoint 8-m-row slab; n outer, m inner).
// __launch_bounds__(256,4): 4 blocks/CU. NOTE: (256,5) regresses hard — VGPR budget
// drops below the ~100 live regs (64 acc + frags + addrs), compiler spills to
// scratch (round 6: WRITE_SIZE 90->503 MB, MfmaUtil 38->12%, 99->286 us). Keep 4.
// MODE 3: C0 fp32 = A0@B + R1
// MODE 4: C0 fp32 = R1 + bf2f(R2) * (A0@B)
// MODE 5: batched QKV via z: A=A0+z*M*K, B=BT0+z*N*K, C=(u16*)C0+z*M*N;
//         z<2 -> bf16(v), z==2 -> sigmoid bf16
// MODE 6: merged FFN: bx<32 -> A0(xk2)@Ck cols, relu^2 bf16 -> C0 (stride 4096);
//         bx>=32 -> A1(xr2)@Cr cols, sigmoid bf16 -> C1 (stride 1024).

template <int MODE>
__launch_bounds__(256, 4)
__global__ void gemm_bt(const u16* __restrict__ A0, const u16* __restrict__ A1,
                        const u16* __restrict__ BT0,
                        const float* R1, const u16* R2,
                        void* C0, void* C1, int M, int N, int K) {
  __shared__ u16 lA[128 * 64];
  __shared__ u16 lB[128 * 64];
  int tid = threadIdx.x;
  int lane = tid & 63;
  int wid = tid >> 6;
  int wy = wid >> 1, wx = wid & 1;

  const u16* A = A0;
  const u16* BT = BT0;
  void* Cout = C0;
  if (MODE == 5) {
    int z = blockIdx.z;
    A = A0 + (size_t)z * M * K;
    BT = BT0 + (size_t)z * N * K;
    Cout = (void*)((u16*)C0 + (size_t)z * M * N);
  }

  // XCD-slab raster: flat&7 = m-slab (requires gridDim.y==64)
  int bx = blockIdx.x, by = blockIdx.y;
  {
    int flat = by * gridDim.x + bx;
    int j = flat >> 3;
    by = (flat & 7) * 8 + (j & 7);
    bx = j >> 3;
  }
  int m0 = by * 128, n0 = bx * 128;

  bool isCr = false;
  if (MODE == 6) {
    isCr = (bx >= 32);
    A = isCr ? A1 : A0;   // Cr columns need the r-mix activations
  }

  int rlo = lane & 15;
  // staging addressing: chunk i = q*256+tid; r=i>>3, pc=i&7, c=(pc-r)&7 (q-indep)
  int rr = tid >> 3;
  int cc = ((tid & 7) - rr) & 7;
  const u16* gA = A + (size_t)(m0 + rr) * K + cc * 8;
  const u16* gB = BT + (size_t)(n0 + rr) * K + cc * 8;
  u16* ldsA = lA + wid * 512;
  u16* ldsB = lB + wid * 512;
  size_t qstep = (size_t)32 * K;

  floatx4 acc[4][4];
#pragma unroll
  for (int mi = 0; mi < 4; mi++)
#pragma unroll
    for (int ni = 0; ni < 4; ni++)
#pragma unroll
      for (int e = 0; e < 4; e++) acc[mi][ni][e] = 0.0f;

  for (int kt = 0; kt < K; kt += 64) {
    __syncthreads();
#pragma unroll
    for (int q = 0; q < 4; q++) {
      __builtin_amdgcn_global_load_lds(gA + q * qstep + kt, ldsA + q * 2048, 16, 0, 0);
      __builtin_amdgcn_global_load_lds(gB + q * qstep + kt, ldsB + q * 2048, 16, 0, 0);
    }
    __syncthreads();
    short8 af[2][4], bfr[2][4];
#pragma unroll
    for (int s = 0; s < 2; s++) {
      int cbase = s * 4 + (lane >> 4);
#pragma unroll
      for (int mi = 0; mi < 4; mi++) {
        int row = wy * 64 + mi * 16 + rlo;
        af[s][mi] = *(const short8*)&lA[row * 64 + (((cbase + row) & 7) << 3)];
      }
#pragma unroll
      for (int ni = 0; ni < 4; ni++) {
        int row = wx * 64 + ni * 16 + rlo;
        bfr[s][ni] = *(const short8*)&lB[row * 64 + (((cbase + row) & 7) << 3)];
      }
    }
#pragma unroll
    for (int s = 0; s < 2; s++)
#pragma unroll
      for (int mi = 0; mi < 4; mi++)
#pragma unroll
        for (int ni = 0; ni < 4; ni++)
          acc[mi][ni] =
              __builtin_amdgcn_mfma_f32_16x16x32_bf16(af[s][mi], bfr[s][ni], acc[mi][ni], 0, 0, 0);
  }

  int rbase = (lane >> 4) * 4;
#pragma unroll
  for (int mi = 0; mi < 4; mi++) {
#pragma unroll
    for (int ni = 0; ni < 4; ni++) {
#pragma unroll
      for (int r = 0; r < 4; r++) {
        int row = m0 + wy * 64 + mi * 16 + rbase + r;
        int col = n0 + wx * 64 + ni * 16 + rlo;
        float v = acc[mi][ni][r];
        if (MODE == 6) {
          if (!isCr) {
            float tpos = fmaxf(v, 0.0f);
            ((u16*)C0)[(size_t)row * 4096 + col] = f2bf(tpos * tpos);
          } else {
            ((u16*)C1)[(size_t)row * 1024 + (col - 4096)] = f2bf(sigmoidf_(v));
          }
        } else {
          size_t idx = (size_t)row * N + col;
          if (MODE == 3) {
            ((float*)Cout)[idx] = v + R1[idx];
          } else if (MODE == 4) {
            ((float*)Cout)[idx] = R1[idx] + bf2f(R2[idx]) * v;
          } else if (MODE == 5) {
            ((u16*)Cout)[idx] = (blockIdx.z == 2) ? f2bf(sigmoidf_(v)) : f2bf(v);
          }
        }
      }
    }
  }
}

extern "C" void kernel_launch(void* const* d_in, const int* in_sizes, int n_in,
                              void* d_out, int out_size, void* d_ws, size_t ws_size,
                              hipStream_t stream) {
  const float* x    = (const float*)d_in[0];
  const float* attx = (const float*)d_in[1];
  const float* aa0  = (const float*)d_in[2];
  const float* bb0  = (const float*)d_in[3];
  const float* pp0  = (const float*)d_in[4];
  const float* ffnx = (const float*)d_in[5];
  const float* ln1g = (const float*)d_in[6];
  const float* ln1b = (const float*)d_in[7];
  const float* ln2g = (const float*)d_in[8];
  const float* ln2b = (const float*)d_in[9];
  const float* mk   = (const float*)d_in[10];
  const float* mv   = (const float*)d_in[11];
  const float* mr   = (const float*)d_in[12];
  const float* decay= (const float*)d_in[13];
  const float* first= (const float*)d_in[14];
  const float* Wk   = (const float*)d_in[15];
  const float* Wv   = (const float*)d_in[16];
  const float* Wr   = (const float*)d_in[17];
  const float* Wo   = (const float*)d_in[18];
  const float* cmk  = (const float*)d_in[19];
  const float* cmr  = (const float*)d_in[20];
  const float* Ck   = (const float*)d_in[21];
  const float* Cr   = (const float*)d_in[22];
  const float* Cv   = (const float*)d_in[23];

  float* out      = (float*)d_out;
  float* xn_last  = out + (size_t)BB * TT * DD;
  float* aa_out   = xn_last + BB * DD;
  float* bb_out   = aa_out + BB * DD;
  float* pp_out   = bb_out + BB * DD;
  float* xn2_last = pp_out + BB * DD;
  float* x1 = out;  // x1 lives in the out buffer

  char* ws = (char*)d_ws;
  const size_t MB = 1024ull * 1024ull;
  u16* WT4   = (u16*)(ws + 0 * MB);     // Wk,Wv,Wr,Wo transposed bf16, 2MB each
  u16* WkT   = WT4;
  u16* WoT   = WT4 + 3u * 1024 * 1024;
  u16* CkCrT = (u16*)(ws + 8 * MB);     // [5120,1024] bf16 = 10MB (Ck rows 0..4095, Cr rows 4096..5119)
  u16* CrTd  = CkCrT + (size_t)4096 * 1024;
  u16* CvT   = (u16*)(ws + 18 * MB);    // 8MB  [1024,4096]
  u16* xk    = (u16*)(ws + 26 * MB);    // 16MB each, contiguous for batched QKV A
  u16* xv    = (u16*)(ws + 42 * MB);
  u16* xr    = (u16*)(ws + 58 * MB);
  u16* kbuf  = (u16*)(ws + 74 * MB);    // 16MB bf16 each, contiguous for batched QKV C
  u16* vbuf  = (u16*)(ws + 90 * MB);
  u16* sigr  = (u16*)(ws + 106 * MB);
  float* sab = (float*)(ws + 122 * MB); // 1MB each
  float* sbb = (float*)(ws + 123 * MB);
  float* psb = (float*)(ws + 124 * MB);
  float* pab = (float*)(ws + 125 * MB);
  float* pbb = (float*)(ws + 126 * MB);
  float* ppb = (float*)(ws + 127 * MB);
  // reuse (lifetimes disjoint):
  u16* rmb   = (u16*)(ws + 26 * MB);    // over xk (dead after QKV GEMM)
  u16* xk2   = (u16*)(ws + 26 * MB);    // over rmb (dead after Wo GEMM)
  u16* xr2   = (u16*)(ws + 42 * MB);    // over xv
  u16* sigr2 = (u16*)(ws + 58 * MB);    // over xr
  u16* kc    = (u16*)(ws + 74 * MB);    // 64MB over kbuf/vbuf/sigr/s* (all dead after chunk_out)

  // merged prologue: ln1mix (8192) + square transposes (5120) + Ck (4096) + Cv (4096)
  prologue_kernel<<<MM + 5120 + 4096 + 4096, 256, 0, stream>>>(
      x, attx, ln1g, ln1b, mk, mv, mr, xk, xv, xr, xn_last,
      Wk, Wv, Wr, Wo, Cr, Ck, Cv, WT4, CrTd, CkCrT, CvT);

  // batched QKV: z=0 -> kbuf (bf16), z=1 -> vbuf (bf16), z=2 -> sigr (sigmoid bf16)
  gemm_bt<5><<<dim3(8, 64, 3), 256, 0, stream>>>(xk, nullptr, WkT, nullptr, nullptr,
                                                 kbuf, nullptr, MM, 1024, 1024);

  wkv_chunk_sum<<<NCHAN * NCH / 256, 256, 0, stream>>>(kbuf, vbuf, decay, sab, sbb, psb);
  wkv_chunk_scan<<<NCHAN / 256, 256, 0, stream>>>(sab, sbb, psb, decay, aa0, bb0, pp0,
                                                  pab, pbb, ppb, aa_out, bb_out, pp_out);
  wkv_chunk_out<<<NCHAN * NCH / 256, 256, 0, stream>>>(kbuf, vbuf, sigr, decay, first,
                                                       pab, pbb, ppb, rmb);

  gemm_bt<3><<<dim3(8, 64), 256, 0, stream>>>(rmb, nullptr, WoT, x, nullptr,
                                              x1, nullptr, MM, 1024, 1024);

  ln2mix_kernel<<<MM, 256, 0, stream>>>(x1, ffnx, ln2g, ln2b, cmk, cmr, xk2, xr2, xn2_last);

  // merged FFN [Ck|Cr]: bx<32 uses xk2 -> kc (relu^2), bx>=32 uses xr2 -> sigr2 (sigmoid)
  gemm_bt<6><<<dim3(40, 64), 256, 0, stream>>>(xk2, xr2, CkCrT, nullptr, nullptr,
                                               kc, sigr2, MM, 5120, 1024);

  gemm_bt<4><<<dim3(8, 64), 256, 0, stream>>>(kc, nullptr, CvT, x1, sigr2,
                                              out, nullptr, MM, 1024, 4096);
}

// Round 9
// 496.239 us; speedup vs baseline: 1.8435x; 1.0152x over previous
//
#include <hip/hip_runtime.h>

#define TT 1024
#define DD 1024
#define BB 8
#define FF 4096
#define MM (BB * TT)
#define CHL 32                 // WKV chunk length
#define NCH (TT / CHL)         // 32 chunks
#define NCHAN (BB * DD)        // 8192 channels

typedef unsigned short u16;
typedef unsigned int u32;

typedef __attribute__((ext_vector_type(8))) short short8;
typedef __attribute__((ext_vector_type(4))) float floatx4;

__device__ __forceinline__ u16 f2bf(float f) {
  u32 u = __float_as_uint(f);
  u32 r = (u + 0x7fffu + ((u >> 16) & 1u)) >> 16;
  return (u16)r;
}
__device__ __forceinline__ float bf2f(u16 h) { return __uint_as_float(((u32)h) << 16); }
__device__ __forceinline__ float sigmoidf_(float v) { return 1.0f / (1.0f + __expf(-v)); }

// ---------------- prologue: ln1mix (blocks 0..8191) + Wk/Wv/Wr transposes ----------------
__global__ __launch_bounds__(256) void prologue_kernel(
    const float* __restrict__ x, const float* __restrict__ attx,
    const float* __restrict__ g, const float* __restrict__ be,
    const float* __restrict__ mk, const float* __restrict__ mv, const float* __restrict__ mr,
    u16* __restrict__ xk, u16* __restrict__ xv, u16* __restrict__ xr,
    float* __restrict__ xn_last,
    const float* __restrict__ Wk, const float* __restrict__ Wv, const float* __restrict__ Wr,
    u16* __restrict__ WT4) {
  int id = blockIdx.x;
  int tid = threadIdx.x;
  __shared__ float tile[32][33];
  __shared__ float red[4][4];

  if (id < MM) {
    // ---- ln1mix ----
    int row = id;
    int b = row >> 10, t = row & (TT - 1);
    float4 xc = ((const float4*)(x + (size_t)row * DD))[tid];
    float4 xp = (t == 0) ? ((const float4*)(attx + (size_t)b * DD))[tid]
                         : ((const float4*)(x + (size_t)(row - 1) * DD))[tid];
    float sc = xc.x + xc.y + xc.z + xc.w;
    float qc = xc.x * xc.x + xc.y * xc.y + xc.z * xc.z + xc.w * xc.w;
    float sp = xp.x + xp.y + xp.z + xp.w;
    float qp = xp.x * xp.x + xp.y * xp.y + xp.z * xp.z + xp.w * xp.w;
#pragma unroll
    for (int o = 32; o > 0; o >>= 1) {
      sc += __shfl_xor(sc, o); qc += __shfl_xor(qc, o);
      sp += __shfl_xor(sp, o); qp += __shfl_xor(qp, o);
    }
    int lane = tid & 63, wid = tid >> 6;
    if (lane == 0) { red[wid][0] = sc; red[wid][1] = qc; red[wid][2] = sp; red[wid][3] = qp; }
    __syncthreads();
    sc = red[0][0] + red[1][0] + red[2][0] + red[3][0];
    qc = red[0][1] + red[1][1] + red[2][1] + red[3][1];
    sp = red[0][2] + red[1][2] + red[2][2] + red[3][2];
    qp = red[0][3] + red[1][3] + red[2][3] + red[3][3];
    const float inv = 1.0f / (float)DD;
    float muc = sc * inv, varc = qc * inv - muc * muc;
    float rc = rsqrtf(varc + 1e-3f);
    float mup = sp * inv, varp = qp * inv - mup * mup;
    float rp = rsqrtf(varp + 1e-3f);
    float4 gg = ((const float4*)g)[tid];
    float4 bb = ((const float4*)be)[tid];
    float4 k4 = ((const float4*)mk)[tid];
    float4 v4 = ((const float4*)mv)[tid];
    float4 r4 = ((const float4*)mr)[tid];
    float xcv[4] = {xc.x, xc.y, xc.z, xc.w};
    float xpv[4] = {xp.x, xp.y, xp.z, xp.w};
    float gv[4] = {gg.x, gg.y, gg.z, gg.w};
    float bv[4] = {bb.x, bb.y, bb.z, bb.w};
    float kv[4] = {k4.x, k4.y, k4.z, k4.w};
    float vv[4] = {v4.x, v4.y, v4.z, v4.w};
    float rv[4] = {r4.x, r4.y, r4.z, r4.w};
    u16 ok[4], ov[4], orr[4];
    float nc[4];
#pragma unroll
    for (int i = 0; i < 4; i++) {
      nc[i] = (xcv[i] - muc) * rc * gv[i] + bv[i];
      float np = (t == 0) ? xpv[i] : ((xpv[i] - mup) * rp * gv[i] + bv[i]);
      ok[i] = f2bf(nc[i] * kv[i] + np * (1.0f - kv[i]));
      ov[i] = f2bf(nc[i] * vv[i] + np * (1.0f - vv[i]));
      orr[i] = f2bf(nc[i] * rv[i] + np * (1.0f - rv[i]));
    }
    size_t o4 = (size_t)row * (DD / 4) + tid;
    ((ushort4*)xk)[o4] = make_ushort4(ok[0], ok[1], ok[2], ok[3]);
    ((ushort4*)xv)[o4] = make_ushort4(ov[0], ov[1], ov[2], ov[3]);
    ((ushort4*)xr)[o4] = make_ushort4(orr[0], orr[1], orr[2], orr[3]);
    if (t == TT - 1)
      ((float4*)xn_last)[(size_t)b * (DD / 4) + tid] = make_float4(nc[0], nc[1], nc[2], nc[3]);
    return;
  }

  // ---- Wk/Wv/Wr transposes (3072 blocks) ----
  id -= MM;
  int tx = tid & 31, ty = tid >> 5;
  int z = id >> 10, i = id & 1023;
  const float* s3[3] = {Wk, Wv, Wr};
  const float* in = s3[z];
  u16* outp = WT4 + (size_t)z * 1024 * 1024;
  int bx = i & 31, by = i >> 5;
  int n0 = bx * 32, k0 = by * 32;
#pragma unroll
  for (int j = 0; j < 32; j += 8)
    tile[ty + j][tx] = in[(size_t)(k0 + ty + j) * 1024 + (n0 + tx)];
  __syncthreads();
#pragma unroll
  for (int j = 0; j < 32; j += 8)
    outp[(size_t)(n0 + ty + j) * 1024 + (k0 + tx)] = f2bf(tile[tx][ty + j]);
}

// ---------------- LN2 + token shift + 2 mixes -> bf16 ----------------
__global__ void ln2mix_kernel(const float* __restrict__ x1, const float* __restrict__ ffnx,
                              const float* __restrict__ g, const float* __restrict__ be,
                              const float* __restrict__ cmk, const float* __restrict__ cmr,
                              u16* __restrict__ xk2, u16* __restrict__ xr2,
                              float* __restrict__ xn2_last) {
  int row = blockIdx.x, tid = threadIdx.x;
  int b = row >> 10, t = row & (TT - 1);
  float4 xc = ((const float4*)(x1 + (size_t)row * DD))[tid];
  float4 xp = (t == 0) ? ((const float4*)(ffnx + (size_t)b * DD))[tid]
                       : ((const float4*)(x1 + (size_t)(row - 1) * DD))[tid];
  float sc = xc.x + xc.y + xc.z + xc.w;
  float qc = xc.x * xc.x + xc.y * xc.y + xc.z * xc.z + xc.w * xc.w;
  float sp = xp.x + xp.y + xp.z + xp.w;
  float qp = xp.x * xp.x + xp.y * xp.y + xp.z * xp.z + xp.w * xp.w;
#pragma unroll
  for (int o = 32; o > 0; o >>= 1) {
    sc += __shfl_xor(sc, o); qc += __shfl_xor(qc, o);
    sp += __shfl_xor(sp, o); qp += __shfl_xor(qp, o);
  }
  __shared__ float red[4][4];
  int lane = tid & 63, wid = tid >> 6;
  if (lane == 0) { red[wid][0] = sc; red[wid][1] = qc; red[wid][2] = sp; red[wid][3] = qp; }
  __syncthreads();
  sc = red[0][0] + red[1][0] + red[2][0] + red[3][0];
  qc = red[0][1] + red[1][1] + red[2][1] + red[3][1];
  sp = red[0][2] + red[1][2] + red[2][2] + red[3][2];
  qp = red[0][3] + red[1][3] + red[2][3] + red[3][3];
  const float inv = 1.0f / (float)DD;
  float muc = sc * inv, varc = qc * inv - muc * muc;
  float rc = rsqrtf(varc + 1e-3f);
  float mup = sp * inv, varp = qp * inv - mup * mup;
  float rp = rsqrtf(varp + 1e-3f);
  float4 gg = ((const float4*)g)[tid];
  float4 bb = ((const float4*)be)[tid];
  float4 k4 = ((const float4*)cmk)[tid];
  float4 r4 = ((const float4*)cmr)[tid];
  float xcv[4] = {xc.x, xc.y, xc.z, xc.w};
  float xpv[4] = {xp.x, xp.y, xp.z, xp.w};
  float gv[4] = {gg.x, gg.y, gg.z, gg.w};
  float bv[4] = {bb.x, bb.y, bb.z, bb.w};
  float kv[4] = {k4.x, k4.y, k4.z, k4.w};
  float rv[4] = {r4.x, r4.y, r4.z, r4.w};
  u16 ok[4], orr[4];
  float nc[4];
#pragma unroll
  for (int i = 0; i < 4; i++) {
    nc[i] = (xcv[i] - muc) * rc * gv[i] + bv[i];
    float np = (t == 0) ? xpv[i] : ((xpv[i] - mup) * rp * gv[i] + bv[i]);
    ok[i] = f2bf(nc[i] * kv[i] + np * (1.0f - kv[i]));
    orr[i] = f2bf(nc[i] * rv[i] + np * (1.0f - rv[i]));
  }
  size_t o4 = (size_t)row * (DD / 4) + tid;
  ((ushort4*)xk2)[o4] = make_ushort4(ok[0], ok[1], ok[2], ok[3]);
  ((ushort4*)xr2)[o4] = make_ushort4(orr[0], orr[1], orr[2], orr[3]);
  if (t == TT - 1)
    ((float4*)xn2_last)[(size_t)b * (DD / 4) + tid] = make_float4(nc[0], nc[1], nc[2], nc[3]);
}

// ================= chunked WKV scan (k/v in bf16), 3 kernels — proven =================
// (cooperative fusion attempt in round 8 failed: hipLaunchCooperativeKernel
//  co-residency validation rejects 512x512 at this VGPR count; launch silently
//  skipped -> rmb stale. Do NOT re-fuse without checking the return code.)
__global__ void wkv_chunk_sum(const u16* __restrict__ K, const u16* __restrict__ V,
                              const float* __restrict__ decay,
                              float* __restrict__ sa, float* __restrict__ sb,
                              float* __restrict__ ps) {
  int f = blockIdx.x * 256 + threadIdx.x;           // 0 .. NCHAN*NCH-1
  int d = f & (DD - 1);
  int bc = f >> 10;
  int b = bc & (BB - 1);
  int chunk = bc >> 3;
  float w = -__expf(decay[d]);
  const u16* kp = K + ((size_t)(b * TT + chunk * CHL)) * DD + d;
  const u16* vp = V + ((size_t)(b * TT + chunk * CHL)) * DD + d;
  float aa = 0.0f, bb = 0.0f, pp = -1e30f;
#pragma unroll
  for (int j = 0; j < CHL; j++) {
    float kt = bf2f(kp[(size_t)j * DD]);
    float vt = bf2f(vp[(size_t)j * DD]);
    float ww2 = pp + w;
    float p2 = fmaxf(ww2, kt);
    float e1 = __expf(ww2 - p2);
    float e2 = __expf(kt - p2);
    aa = e1 * aa + e2 * vt;
    bb = e1 * bb + e2;
    pp = p2;
  }
  int ch = b * DD + d;
  size_t s = (size_t)chunk * NCHAN + ch;
  sa[s] = aa; sb[s] = bb; ps[s] = pp;
}

__global__ void wkv_chunk_scan(const float* __restrict__ sa, const float* __restrict__ sb,
                               const float* __restrict__ ps, const float* __restrict__ decay,
                               const float* __restrict__ aa0, const float* __restrict__ bb0,
                               const float* __restrict__ pp0,
                               float* __restrict__ pa, float* __restrict__ pb,
                               float* __restrict__ ppx,
                               float* __restrict__ aa_out, float* __restrict__ bb_out,
                               float* __restrict__ pp_out) {
  int ch = blockIdx.x * 256 + threadIdx.x;  // 0..NCHAN-1
  int d = ch & (DD - 1);
  float w = -__expf(decay[d]);
  float wL = (float)CHL * w;
  float aa = aa0[ch], bb = bb0[ch], pp = pp0[ch];
  float lsa[NCH], lsb[NCH], lps[NCH];
#pragma unroll
  for (int j = 0; j < NCH; j++) {
    size_t s = (size_t)j * NCHAN + ch;
    lsa[j] = sa[s]; lsb[j] = sb[s]; lps[j] = ps[s];
  }
#pragma unroll
  for (int j = 0; j < NCH; j++) {
    size_t s = (size_t)j * NCHAN + ch;
    pa[s] = aa; pb[s] = bb; ppx[s] = pp;
    float pw = pp + wL;
    float pn = fmaxf(pw, lps[j]);
    float e1 = __expf(pw - pn);
    float e2 = __expf(lps[j] - pn);
    aa = e1 * aa + e2 * lsa[j];
    bb = e1 * bb + e2 * lsb[j];
    pp = pn;
  }
  aa_out[ch] = aa; bb_out[ch] = bb; pp_out[ch] = pp;
}

__global__ void wkv_chunk_out(const u16* __restrict__ K, const u16* __restrict__ V,
                              const u16* __restrict__ sigr, const float* __restrict__ decay,
                              const float* __restrict__ first,
                              const float* __restrict__ pa, const float* __restrict__ pb,
                              const float* __restrict__ ppx, u16* __restrict__ rm) {
  int f = blockIdx.x * 256 + threadIdx.x;
  int d = f & (DD - 1);
  int bc = f >> 10;
  int b = bc & (BB - 1);
  int chunk = bc >> 3;
  float w = -__expf(decay[d]);
  float u = first[d];
  int ch = b * DD + d;
  size_t s = (size_t)chunk * NCHAN + ch;
  float aa = pa[s], bb = pb[s], pp = ppx[s];
  size_t base = ((size_t)(b * TT + chunk * CHL)) * DD + d;
  const u16* kp = K + base;
  const u16* vp = V + base;
  const u16* rp = sigr + base;
  u16* op = rm + base;
#pragma unroll
  for (int j = 0; j < CHL; j++) {
    float kt = bf2f(kp[(size_t)j * DD]);
    float vt = bf2f(vp[(size_t)j * DD]);
    float ww = u + kt;
    float p = fmaxf(pp, ww);
    float e1 = __expf(pp - p);
    float e2 = __expf(ww - p);
    float wkv = __fdividef(e1 * aa + e2 * vt, e1 * bb + e2);
    op[(size_t)j * DD] = f2bf(bf2f(rp[(size_t)j * DD]) * wkv);
    float ww2 = pp + w;
    float p2 = fmaxf(ww2, kt);
    float e1b = __expf(ww2 - p2);
    float e2b = __expf(kt - p2);
    aa = e1b * aa + e2b * vt;
    bb = e1b * bb + e2b;
    pp = p2;
  }
}

// ---------------- bf16 MFMA GEMM, C = A[M,K] @ B (BT given as [N,K]) ----------------
// BK=64, global_load_lds width-16 staging, row-swizzled LDS (pc=(c+r)&7),
// XCD-slab rasterization (flat&7 -> disjoint 8-m-row slab; n outer, m inner).
// __launch_bounds__(256,4): 4 blocks/CU. NOTE: (256,5) regresses hard — VGPR budget
// drops below the ~100 live regs, compiler spills to scratch (round 6: WRITE_SIZE
// 90->503 MB, MfmaUtil 38->12%, 99->286 us). Keep 4.
// MODE 3: C0 fp32 = A0@B + R1
// MODE 4: C0 fp32 = R1 + bf2f(R2) * (A0@B)
// MODE 5: batched QKV via z<3: A=A0+z*M*K, B=BT0+z*N*K, C=(u16*)C0+z*M*N;
//         z<2 -> bf16(v), z==2 -> sigmoid bf16.
//         z>=3: memory-only weight-transpose blocks (Wo,Cr,Ck,Cv) that backfill
//         the machine while GEMM blocks own the compute pipes.
// MODE 6: merged FFN: bx<32 -> A0(xk2)@Ck cols, relu^2 bf16 -> C0 (stride 4096);
//         bx>=32 -> A1(xr2)@Cr cols, sigmoid bf16 -> C1 (stride 1024).

template <int MODE>
__launch_bounds__(256, 4)
__global__ void gemm_bt(const u16* __restrict__ A0, const u16* __restrict__ A1,
                        const u16* __restrict__ BT0,
                        const float* R1, const u16* R2,
                        void* C0, void* C1, int M, int N, int K,
                        const float* TW0, const float* TW1, const float* TW2, const float* TW3,
                        u16* TO0, u16* TO1, u16* TO2, u16* TO3) {
  __shared__ u16 lA[128 * 64];
  __shared__ u16 lB[128 * 64];
  int tid = threadIdx.x;

  if (MODE == 5 && blockIdx.z >= 3) {
    // ---- transpose blocks: id in 0..10239 (Wo 1024, Cr 1024, Ck 4096, Cv 4096) ----
    int id = (blockIdx.z - 3) * 512 + blockIdx.y * gridDim.x + blockIdx.x;
    float* tile = (float*)lA;  // 32*33 floats = 4224 B
    int tx = tid & 31, ty = tid >> 5;
    const float* in;
    u16* outp;
    int K2, N2, bx2, by2;
    if (id < 1024) {
      in = TW0; outp = TO0; K2 = 1024; N2 = 1024; bx2 = id & 31; by2 = id >> 5;
    } else if (id < 2048) {
      int i = id - 1024;
      in = TW1; outp = TO1; K2 = 1024; N2 = 1024; bx2 = i & 31; by2 = i >> 5;
    } else if (id < 6144) {
      int i = id - 2048;
      in = TW2; outp = TO2; K2 = 1024; N2 = 4096; bx2 = i & 127; by2 = i >> 7;
    } else {
      int i = id - 6144;
      in = TW3; outp = TO3; K2 = 4096; N2 = 1024; bx2 = i & 31; by2 = i >> 5;
    }
    int n0 = bx2 * 32, k0 = by2 * 32;
#pragma unroll
    for (int j = 0; j < 32; j += 8)
      tile[(ty + j) * 33 + tx] = in[(size_t)(k0 + ty + j) * N2 + (n0 + tx)];
    __syncthreads();
#pragma unroll
    for (int j = 0; j < 32; j += 8)
      outp[(size_t)(n0 + ty + j) * K2 + (k0 + tx)] = f2bf(tile[tx * 33 + (ty + j)]);
    return;
  }

  int lane = tid & 63;
  int wid = tid >> 6;
  int wy = wid >> 1, wx = wid & 1;

  const u16* A = A0;
  const u16* BT = BT0;
  void* Cout = C0;
  if (MODE == 5) {
    int z = blockIdx.z;
    A = A0 + (size_t)z * M * K;
    BT = BT0 + (size_t)z * N * K;
    Cout = (void*)((u16*)C0 + (size_t)z * M * N);
  }

  // XCD-slab raster: flat&7 = m-slab (requires gridDim.y==64)
  int bx = blockIdx.x, by = blockIdx.y;
  {
    int flat = by * gridDim.x + bx;
    int j = flat >> 3;
    by = (flat & 7) * 8 + (j & 7);
    bx = j >> 3;
  }
  int m0 = by * 128, n0 = bx * 128;

  bool isCr = false;
  if (MODE == 6) {
    isCr = (bx >= 32);
    A = isCr ? A1 : A0;   // Cr columns need the r-mix activations
  }

  int rlo = lane & 15;
  // staging addressing: chunk i = q*256+tid; r=i>>3, pc=i&7, c=(pc-r)&7 (q-indep)
  int rr = tid >> 3;
  int cc = ((tid & 7) - rr) & 7;
  const u16* gA = A + (size_t)(m0 + rr) * K + cc * 8;
  const u16* gB = BT + (size_t)(n0 + rr) * K + cc * 8;
  u16* ldsA = lA + wid * 512;
  u16* ldsB = lB + wid * 512;
  size_t qstep = (size_t)32 * K;

  floatx4 acc[4][4];
#pragma unroll
  for (int mi = 0; mi < 4; mi++)
#pragma unroll
    for (int ni = 0; ni < 4; ni++)
#pragma unroll
      for (int e = 0; e < 4; e++) acc[mi][ni][e] = 0.0f;

  for (int kt = 0; kt < K; kt += 64) {
    __syncthreads();
#pragma unroll
    for (int q = 0; q < 4; q++) {
      __builtin_amdgcn_global_load_lds(gA + q * qstep + kt, ldsA + q * 2048, 16, 0, 0);
      __builtin_amdgcn_global_load_lds(gB + q * qstep + kt, ldsB + q * 2048, 16, 0, 0);
    }
    __syncthreads();
    short8 af[2][4], bfr[2][4];
#pragma unroll
    for (int s = 0; s < 2; s++) {
      int cbase = s * 4 + (lane >> 4);
#pragma unroll
      for (int mi = 0; mi < 4; mi++) {
        int row = wy * 64 + mi * 16 + rlo;
        af[s][mi] = *(const short8*)&lA[row * 64 + (((cbase + row) & 7) << 3)];
      }
#pragma unroll
      for (int ni = 0; ni < 4; ni++) {
        int row = wx * 64 + ni * 16 + rlo;
        bfr[s][ni] = *(const short8*)&lB[row * 64 + (((cbase + row) & 7) << 3)];
      }
    }
#pragma unroll
    for (int s = 0; s < 2; s++)
#pragma unroll
      for (int mi = 0; mi < 4; mi++)
#pragma unroll
        for (int ni = 0; ni < 4; ni++)
          acc[mi][ni] =
              __builtin_amdgcn_mfma_f32_16x16x32_bf16(af[s][mi], bfr[s][ni], acc[mi][ni], 0, 0, 0);
  }

  int rbase = (lane >> 4) * 4;
#pragma unroll
  for (int mi = 0; mi < 4; mi++) {
#pragma unroll
    for (int ni = 0; ni < 4; ni++) {
#pragma unroll
      for (int r = 0; r < 4; r++) {
        int row = m0 + wy * 64 + mi * 16 + rbase + r;
        int col = n0 + wx * 64 + ni * 16 + rlo;
        float v = acc[mi][ni][r];
        if (MODE == 6) {
          if (!isCr) {
            float tpos = fmaxf(v, 0.0f);
            ((u16*)C0)[(size_t)row * 4096 + col] = f2bf(tpos * tpos);
          } else {
            ((u16*)C1)[(size_t)row * 1024 + (col - 4096)] = f2bf(sigmoidf_(v));
          }
        } else {
          size_t idx = (size_t)row * N + col;
          if (MODE == 3) {
            ((float*)Cout)[idx] = v + R1[idx];
          } else if (MODE == 4) {
            ((float*)Cout)[idx] = R1[idx] + bf2f(R2[idx]) * v;
          } else if (MODE == 5) {
            ((u16*)Cout)[idx] = (blockIdx.z == 2) ? f2bf(sigmoidf_(v)) : f2bf(v);
          }
        }
      }
    }
  }
}

extern "C" void kernel_launch(void* const* d_in, const int* in_sizes, int n_in,
                              void* d_out, int out_size, void* d_ws, size_t ws_size,
                              hipStream_t stream) {
  const float* x    = (const float*)d_in[0];
  const float* attx = (const float*)d_in[1];
  const float* aa0  = (const float*)d_in[2];
  const float* bb0  = (const float*)d_in[3];
  const float* pp0  = (const float*)d_in[4];
  const float* ffnx = (const float*)d_in[5];
  const float* ln1g = (const float*)d_in[6];
  const float* ln1b = (const float*)d_in[7];
  const float* ln2g = (const float*)d_in[8];
  const float* ln2b = (const float*)d_in[9];
  const float* mk   = (const float*)d_in[10];
  const float* mv   = (const float*)d_in[11];
  const float* mr   = (const float*)d_in[12];
  const float* decay= (const float*)d_in[13];
  const float* first= (const float*)d_in[14];
  const float* Wk   = (const float*)d_in[15];
  const float* Wv   = (const float*)d_in[16];
  const float* Wr   = (const float*)d_in[17];
  const float* Wo   = (const float*)d_in[18];
  const float* cmk  = (const float*)d_in[19];
  const float* cmr  = (const float*)d_in[20];
  const float* Ck   = (const float*)d_in[21];
  const float* Cr   = (const float*)d_in[22];
  const float* Cv   = (const float*)d_in[23];

  float* out      = (float*)d_out;
  float* xn_last  = out + (size_t)BB * TT * DD;
  float* aa_out   = xn_last + BB * DD;
  float* bb_out   = aa_out + BB * DD;
  float* pp_out   = bb_out + BB * DD;
  float* xn2_last = pp_out + BB * DD;
  float* x1 = out;  // x1 lives in the out buffer

  char* ws = (char*)d_ws;
  const size_t MB = 1024ull * 1024ull;
  u16* WT4   = (u16*)(ws + 0 * MB);     // Wk,Wv,Wr,Wo transposed bf16, 2MB each
  u16* WkT   = WT4;
  u16* WoT   = WT4 + 3u * 1024 * 1024;
  u16* CkCrT = (u16*)(ws + 8 * MB);     // [5120,1024] bf16 = 10MB (Ck rows 0..4095, Cr rows 4096..5119)
  u16* CrTd  = CkCrT + (size_t)4096 * 1024;
  u16* CvT   = (u16*)(ws + 18 * MB);    // 8MB  [1024,4096]
  u16* xk    = (u16*)(ws + 26 * MB);    // 16MB each, contiguous for batched QKV A
  u16* xv    = (u16*)(ws + 42 * MB);
  u16* xr    = (u16*)(ws + 58 * MB);
  u16* kbuf  = (u16*)(ws + 74 * MB);    // 16MB bf16 each, contiguous for batched QKV C
  u16* vbuf  = (u16*)(ws + 90 * MB);
  u16* sigr  = (u16*)(ws + 106 * MB);
  float* sab = (float*)(ws + 122 * MB); // 1MB each
  float* sbb = (float*)(ws + 123 * MB);
  float* psb = (float*)(ws + 124 * MB);
  float* pab = (float*)(ws + 125 * MB);
  float* pbb = (float*)(ws + 126 * MB);
  float* ppb = (float*)(ws + 127 * MB);
  // reuse (lifetimes disjoint):
  u16* rmb   = (u16*)(ws + 26 * MB);    // over xk (dead after QKV GEMM)
  u16* xk2   = (u16*)(ws + 26 * MB);    // over rmb (dead after Wo GEMM)
  u16* xr2   = (u16*)(ws + 42 * MB);    // over xv
  u16* sigr2 = (u16*)(ws + 58 * MB);    // over xr
  u16* kc    = (u16*)(ws + 74 * MB);    // 64MB over kbuf/vbuf/sigr/s* (all dead after chunk_out)

  // prologue: ln1mix (8192) + Wk/Wv/Wr transposes (3072)
  prologue_kernel<<<MM + 3072, 256, 0, stream>>>(
      x, attx, ln1g, ln1b, mk, mv, mr, xk, xv, xr, xn_last, Wk, Wv, Wr, WT4);

  // batched QKV (z<3): z=0 -> kbuf, z=1 -> vbuf, z=2 -> sigr (sigmoid bf16).
  // z=3..22: Wo/Cr/Ck/Cv transpose blocks backfill (memory-only work).
  gemm_bt<5><<<dim3(8, 64, 23), 256, 0, stream>>>(
      xk, nullptr, WkT, nullptr, nullptr, kbuf, nullptr, MM, 1024, 1024,
      Wo, Cr, Ck, Cv, WoT, CrTd, CkCrT, CvT);

  wkv_chunk_sum<<<NCHAN * NCH / 256, 256, 0, stream>>>(kbuf, vbuf, decay, sab, sbb, psb);
  wkv_chunk_scan<<<NCHAN / 256, 256, 0, stream>>>(sab, sbb, psb, decay, aa0, bb0, pp0,
                                                  pab, pbb, ppb, aa_out, bb_out, pp_out);
  wkv_chunk_out<<<NCHAN * NCH / 256, 256, 0, stream>>>(kbuf, vbuf, sigr, decay, first,
                                                       pab, pbb, ppb, rmb);

  gemm_bt<3><<<dim3(8, 64), 256, 0, stream>>>(rmb, nullptr, WoT, x, nullptr,
                                              x1, nullptr, MM, 1024, 1024,
                                              nullptr, nullptr, nullptr, nullptr,
                                              nullptr, nullptr, nullptr, nullptr);

  ln2mix_kernel<<<MM, 256, 0, stream>>>(x1, ffnx, ln2g, ln2b, cmk, cmr, xk2, xr2, xn2_last);

  // merged FFN [Ck|Cr]: bx<32 uses xk2 -> kc (relu^2), bx>=32 uses xr2 -> sigr2 (sigmoid)
  gemm_bt<6><<<dim3(40, 64), 256, 0, stream>>>(xk2, xr2, CkCrT, nullptr, nullptr,
                                               kc, sigr2, MM, 5120, 1024,
                                               nullptr, nullptr, nullptr, nullptr,
                                               nullptr, nullptr, nullptr, nullptr);

  gemm_bt<4><<<dim3(8, 64), 256, 0, stream>>>(kc, nullptr, CvT, x1, sigr2,
                                              out, nullptr, MM, 1024, 4096,
                                              nullptr, nullptr, nullptr, nullptr,
                                              nullptr, nullptr, nullptr, nullptr);
}

// Round 10
// 477.853 us; speedup vs baseline: 1.9144x; 1.0385x over previous
//
#include <hip/hip_runtime.h>

#define TT 1024
#define DD 1024
#define BB 8
#define FF 4096
#define MM (BB * TT)
#define CHL 32                 // WKV chunk length
#define NCH (TT / CHL)         // 32 chunks
#define NCHAN (BB * DD)        // 8192 channels

typedef unsigned short u16;
typedef unsigned int u32;

typedef __attribute__((ext_vector_type(8))) short short8;
typedef __attribute__((ext_vector_type(4))) float floatx4;

__device__ __forceinline__ u16 f2bf(float f) {
  u32 u = __float_as_uint(f);
  u32 r = (u + 0x7fffu + ((u >> 16) & 1u)) >> 16;
  return (u16)r;
}
__device__ __forceinline__ float bf2f(u16 h) { return __uint_as_float(((u32)h) << 16); }
__device__ __forceinline__ float sigmoidf_(float v) { return 1.0f / (1.0f + __expf(-v)); }

// ---------------- prologue: ln1mix (blocks 0..8191) + Wk/Wv/Wr transposes ----------------
__global__ __launch_bounds__(256) void prologue_kernel(
    const float* __restrict__ x, const float* __restrict__ attx,
    const float* __restrict__ g, const float* __restrict__ be,
    const float* __restrict__ mk, const float* __restrict__ mv, const float* __restrict__ mr,
    u16* __restrict__ xk, u16* __restrict__ xv, u16* __restrict__ xr,
    float* __restrict__ xn_last,
    const float* __restrict__ Wk, const float* __restrict__ Wv, const float* __restrict__ Wr,
    u16* __restrict__ WT4) {
  int id = blockIdx.x;
  int tid = threadIdx.x;
  __shared__ float tile[32][33];
  __shared__ float red[4][4];

  if (id < MM) {
    // ---- ln1mix ----
    int row = id;
    int b = row >> 10, t = row & (TT - 1);
    float4 xc = ((const float4*)(x + (size_t)row * DD))[tid];
    float4 xp = (t == 0) ? ((const float4*)(attx + (size_t)b * DD))[tid]
                         : ((const float4*)(x + (size_t)(row - 1) * DD))[tid];
    float sc = xc.x + xc.y + xc.z + xc.w;
    float qc = xc.x * xc.x + xc.y * xc.y + xc.z * xc.z + xc.w * xc.w;
    float sp = xp.x + xp.y + xp.z + xp.w;
    float qp = xp.x * xp.x + xp.y * xp.y + xp.z * xp.z + xp.w * xp.w;
#pragma unroll
    for (int o = 32; o > 0; o >>= 1) {
      sc += __shfl_xor(sc, o); qc += __shfl_xor(qc, o);
      sp += __shfl_xor(sp, o); qp += __shfl_xor(qp, o);
    }
    int lane = tid & 63, wid = tid >> 6;
    if (lane == 0) { red[wid][0] = sc; red[wid][1] = qc; red[wid][2] = sp; red[wid][3] = qp; }
    __syncthreads();
    sc = red[0][0] + red[1][0] + red[2][0] + red[3][0];
    qc = red[0][1] + red[1][1] + red[2][1] + red[3][1];
    sp = red[0][2] + red[1][2] + red[2][2] + red[3][2];
    qp = red[0][3] + red[1][3] + red[2][3] + red[3][3];
    const float inv = 1.0f / (float)DD;
    float muc = sc * inv, varc = qc * inv - muc * muc;
    float rc = rsqrtf(varc + 1e-3f);
    float mup = sp * inv, varp = qp * inv - mup * mup;
    float rp = rsqrtf(varp + 1e-3f);
    float4 gg = ((const float4*)g)[tid];
    float4 bb = ((const float4*)be)[tid];
    float4 k4 = ((const float4*)mk)[tid];
    float4 v4 = ((const float4*)mv)[tid];
    float4 r4 = ((const float4*)mr)[tid];
    float xcv[4] = {xc.x, xc.y, xc.z, xc.w};
    float xpv[4] = {xp.x, xp.y, xp.z, xp.w};
    float gv[4] = {gg.x, gg.y, gg.z, gg.w};
    float bv[4] = {bb.x, bb.y, bb.z, bb.w};
    float kv[4] = {k4.x, k4.y, k4.z, k4.w};
    float vv[4] = {v4.x, v4.y, v4.z, v4.w};
    float rv[4] = {r4.x, r4.y, r4.z, r4.w};
    u16 ok[4], ov[4], orr[4];
    float nc[4];
#pragma unroll
    for (int i = 0; i < 4; i++) {
      nc[i] = (xcv[i] - muc) * rc * gv[i] + bv[i];
      float np = (t == 0) ? xpv[i] : ((xpv[i] - mup) * rp * gv[i] + bv[i]);
      ok[i] = f2bf(nc[i] * kv[i] + np * (1.0f - kv[i]));
      ov[i] = f2bf(nc[i] * vv[i] + np * (1.0f - vv[i]));
      orr[i] = f2bf(nc[i] * rv[i] + np * (1.0f - rv[i]));
    }
    size_t o4 = (size_t)row * (DD / 4) + tid;
    ((ushort4*)xk)[o4] = make_ushort4(ok[0], ok[1], ok[2], ok[3]);
    ((ushort4*)xv)[o4] = make_ushort4(ov[0], ov[1], ov[2], ov[3]);
    ((ushort4*)xr)[o4] = make_ushort4(orr[0], orr[1], orr[2], orr[3]);
    if (t == TT - 1)
      ((float4*)xn_last)[(size_t)b * (DD / 4) + tid] = make_float4(nc[0], nc[1], nc[2], nc[3]);
    return;
  }

  // ---- Wk/Wv/Wr transposes (3072 blocks) ----
  id -= MM;
  int tx = tid & 31, ty = tid >> 5;
  int z = id >> 10, i = id & 1023;
  const float* s3[3] = {Wk, Wv, Wr};
  const float* in = s3[z];
  u16* outp = WT4 + (size_t)z * 1024 * 1024;
  int bx = i & 31, by = i >> 5;
  int n0 = bx * 32, k0 = by * 32;
#pragma unroll
  for (int j = 0; j < 32; j += 8)
    tile[ty + j][tx] = in[(size_t)(k0 + ty + j) * 1024 + (n0 + tx)];
  __syncthreads();
#pragma unroll
  for (int j = 0; j < 32; j += 8)
    outp[(size_t)(n0 + ty + j) * 1024 + (k0 + tx)] = f2bf(tile[tx][ty + j]);
}

// ---------------- LN2 + token shift + 2 mixes -> bf16 ----------------
__global__ void ln2mix_kernel(const float* __restrict__ x1, const float* __restrict__ ffnx,
                              const float* __restrict__ g, const float* __restrict__ be,
                              const float* __restrict__ cmk, const float* __restrict__ cmr,
                              u16* __restrict__ xk2, u16* __restrict__ xr2,
                              float* __restrict__ xn2_last) {
  int row = blockIdx.x, tid = threadIdx.x;
  int b = row >> 10, t = row & (TT - 1);
  float4 xc = ((const float4*)(x1 + (size_t)row * DD))[tid];
  float4 xp = (t == 0) ? ((const float4*)(ffnx + (size_t)b * DD))[tid]
                       : ((const float4*)(x1 + (size_t)(row - 1) * DD))[tid];
  float sc = xc.x + xc.y + xc.z + xc.w;
  float qc = xc.x * xc.x + xc.y * xc.y + xc.z * xc.z + xc.w * xc.w;
  float sp = xp.x + xp.y + xp.z + xp.w;
  float qp = xp.x * xp.x + xp.y * xp.y + xp.z * xp.z + xp.w * xp.w;
#pragma unroll
  for (int o = 32; o > 0; o >>= 1) {
    sc += __shfl_xor(sc, o); qc += __shfl_xor(qc, o);
    sp += __shfl_xor(sp, o); qp += __shfl_xor(qp, o);
  }
  __shared__ float red[4][4];
  int lane = tid & 63, wid = tid >> 6;
  if (lane == 0) { red[wid][0] = sc; red[wid][1] = qc; red[wid][2] = sp; red[wid][3] = qp; }
  __syncthreads();
  sc = red[0][0] + red[1][0] + red[2][0] + red[3][0];
  qc = red[0][1] + red[1][1] + red[2][1] + red[3][1];
  sp = red[0][2] + red[1][2] + red[2][2] + red[3][2];
  qp = red[0][3] + red[1][3] + red[2][3] + red[3][3];
  const float inv = 1.0f / (float)DD;
  float muc = sc * inv, varc = qc * inv - muc * muc;
  float rc = rsqrtf(varc + 1e-3f);
  float mup = sp * inv, varp = qp * inv - mup * mup;
  float rp = rsqrtf(varp + 1e-3f);
  float4 gg = ((const float4*)g)[tid];
  float4 bb = ((const float4*)be)[tid];
  float4 k4 = ((const float4*)cmk)[tid];
  float4 r4 = ((const float4*)cmr)[tid];
  float xcv[4] = {xc.x, xc.y, xc.z, xc.w};
  float xpv[4] = {xp.x, xp.y, xp.z, xp.w};
  float gv[4] = {gg.x, gg.y, gg.z, gg.w};
  float bv[4] = {bb.x, bb.y, bb.z, bb.w};
  float kv[4] = {k4.x, k4.y, k4.z, k4.w};
  float rv[4] = {r4.x, r4.y, r4.z, r4.w};
  u16 ok[4], orr[4];
  float nc[4];
#pragma unroll
  for (int i = 0; i < 4; i++) {
    nc[i] = (xcv[i] - muc) * rc * gv[i] + bv[i];
    float np = (t == 0) ? xpv[i] : ((xpv[i] - mup) * rp * gv[i] + bv[i]);
    ok[i] = f2bf(nc[i] * kv[i] + np * (1.0f - kv[i]));
    orr[i] = f2bf(nc[i] * rv[i] + np * (1.0f - rv[i]));
  }
  size_t o4 = (size_t)row * (DD / 4) + tid;
  ((ushort4*)xk2)[o4] = make_ushort4(ok[0], ok[1], ok[2], ok[3]);
  ((ushort4*)xr2)[o4] = make_ushort4(orr[0], orr[1], orr[2], orr[3]);
  if (t == TT - 1)
    ((float4*)xn2_last)[(size_t)b * (DD / 4) + tid] = make_float4(nc[0], nc[1], nc[2], nc[3]);
}

// ================= chunked WKV scan (k/v in bf16), 2 launches =================
// (cooperative single-launch fusion failed in round 8 — co-residency rejection,
//  launch silently skipped. These are REGULAR launches; the scan_out kernel
//  re-derives each thread's prefix by streaming the L3-hot chunk summaries.)
__global__ void wkv_chunk_sum(const u16* __restrict__ K, const u16* __restrict__ V,
                              const float* __restrict__ decay,
                              float* __restrict__ sa, float* __restrict__ sb,
                              float* __restrict__ ps) {
  int f = blockIdx.x * 256 + threadIdx.x;           // 0 .. NCHAN*NCH-1
  int d = f & (DD - 1);
  int bc = f >> 10;
  int b = bc & (BB - 1);
  int chunk = bc >> 3;
  float w = -__expf(decay[d]);
  const u16* kp = K + ((size_t)(b * TT + chunk * CHL)) * DD + d;
  const u16* vp = V + ((size_t)(b * TT + chunk * CHL)) * DD + d;
  float aa = 0.0f, bb = 0.0f, pp = -1e30f;
#pragma unroll
  for (int j = 0; j < CHL; j++) {
    float kt = bf2f(kp[(size_t)j * DD]);
    float vt = bf2f(vp[(size_t)j * DD]);
    float ww2 = pp + w;
    float p2 = fmaxf(ww2, kt);
    float e1 = __expf(ww2 - p2);
    float e2 = __expf(kt - p2);
    aa = e1 * aa + e2 * vt;
    bb = e1 * bb + e2;
    pp = p2;
  }
  int ch = b * DD + d;
  size_t s = (size_t)chunk * NCHAN + ch;
  sa[s] = aa; sb[s] = bb; ps[s] = pp;
}

// scan_out: prefix from chunk summaries (j < chunk, uniform per block) + replay chunk,
// emit rm = bf16(sigr * wkv); chunk==31 threads write final states.
__global__ void wkv_scan_out(const u16* __restrict__ K, const u16* __restrict__ V,
                             const u16* __restrict__ sigr, const float* __restrict__ decay,
                             const float* __restrict__ first,
                             const float* __restrict__ aa0, const float* __restrict__ bb0,
                             const float* __restrict__ pp0,
                             const float* __restrict__ sa, const float* __restrict__ sb,
                             const float* __restrict__ ps, u16* __restrict__ rm,
                             float* __restrict__ aa_out, float* __restrict__ bb_out,
                             float* __restrict__ pp_out) {
  int f = blockIdx.x * 256 + threadIdx.x;
  int d = f & (DD - 1);
  int bc = f >> 10;
  int b = bc & (BB - 1);
  int chunk = bc >> 3;
  int ch = b * DD + d;
  float w = -__expf(decay[d]);
  float wL = (float)CHL * w;

  float aa = aa0[ch], bb = bb0[ch], pp = pp0[ch];
  for (int j = 0; j < chunk; j++) {
    size_t s = (size_t)j * NCHAN + ch;
    float lsa = sa[s], lsb = sb[s], lps = ps[s];
    float pw = pp + wL;
    float pn = fmaxf(pw, lps);
    float e1 = __expf(pw - pn);
    float e2 = __expf(lps - pn);
    aa = e1 * aa + e2 * lsa;
    bb = e1 * bb + e2 * lsb;
    pp = pn;
  }

  size_t base = ((size_t)(b * TT + chunk * CHL)) * DD + d;
  const u16* kp = K + base;
  const u16* vp = V + base;
  const u16* rp = sigr + base;
  u16* op = rm + base;
  float u = first[d];
#pragma unroll
  for (int j = 0; j < CHL; j++) {
    float kt = bf2f(kp[(size_t)j * DD]);
    float vt = bf2f(vp[(size_t)j * DD]);
    float ww = u + kt;
    float p = fmaxf(pp, ww);
    float e1 = __expf(pp - p);
    float e2 = __expf(ww - p);
    float wkv = __fdividef(e1 * aa + e2 * vt, e1 * bb + e2);
    op[(size_t)j * DD] = f2bf(bf2f(rp[(size_t)j * DD]) * wkv);
    float ww2 = pp + w;
    float p2 = fmaxf(ww2, kt);
    float e1b = __expf(ww2 - p2);
    float e2b = __expf(kt - p2);
    aa = e1b * aa + e2b * vt;
    bb = e1b * bb + e2b;
    pp = p2;
  }
  if (chunk == NCH - 1) { aa_out[ch] = aa; bb_out[ch] = bb; pp_out[ch] = pp; }
}

// ---------------- bf16 MFMA GEMM 128x128 tile ----------------
// BK=64, global_load_lds width-16 staging, row-swizzled LDS (pc=(c+r)&7),
// XCD-slab raster (flat&7 -> disjoint 8-m-row slab; requires gridDim.y==64).
// __launch_bounds__(256,4). NOTE: (256,5) regresses hard (VGPR spill, round 6). Keep 4.
// MODE 5: batched QKV via z<3: A=A0+z*M*K, B=BT0+z*N*K, C=(u16*)C0+z*M*N;
//         z<2 -> bf16(v), z==2 -> sigmoid bf16.
//         z>=3: memory-only weight-transpose blocks (Wo,Cr,Ck,Cv) backfill.
// MODE 6: merged FFN: bx<32 -> A0(xk2)@Ck cols, relu^2 bf16 -> C0 (stride 4096);
//         bx>=32 -> A1(xr2)@Cr cols, sigmoid bf16 -> C1 (stride 1024).

template <int MODE>
__launch_bounds__(256, 4)
__global__ void gemm_bt(const u16* __restrict__ A0, const u16* __restrict__ A1,
                        const u16* __restrict__ BT0,
                        void* C0, void* C1, int M, int N, int K,
                        const float* TW0, const float* TW1, const float* TW2, const float* TW3,
                        u16* TO0, u16* TO1, u16* TO2, u16* TO3) {
  __shared__ u16 lA[128 * 64];
  __shared__ u16 lB[128 * 64];
  int tid = threadIdx.x;

  if (MODE == 5 && blockIdx.z >= 3) {
    // ---- transpose blocks: id in 0..10239 (Wo 1024, Cr 1024, Ck 4096, Cv 4096) ----
    int id = (blockIdx.z - 3) * 512 + blockIdx.y * gridDim.x + blockIdx.x;
    float* tile = (float*)lA;  // 32*33 floats
    int tx = tid & 31, ty = tid >> 5;
    const float* in;
    u16* outp;
    int K2, N2, bx2, by2;
    if (id < 1024) {
      in = TW0; outp = TO0; K2 = 1024; N2 = 1024; bx2 = id & 31; by2 = id >> 5;
    } else if (id < 2048) {
      int i = id - 1024;
      in = TW1; outp = TO1; K2 = 1024; N2 = 1024; bx2 = i & 31; by2 = i >> 5;
    } else if (id < 6144) {
      int i = id - 2048;
      in = TW2; outp = TO2; K2 = 1024; N2 = 4096; bx2 = i & 127; by2 = i >> 7;
    } else {
      int i = id - 6144;
      in = TW3; outp = TO3; K2 = 4096; N2 = 1024; bx2 = i & 31; by2 = i >> 5;
    }
    int n0 = bx2 * 32, k0 = by2 * 32;
#pragma unroll
    for (int j = 0; j < 32; j += 8)
      tile[(ty + j) * 33 + tx] = in[(size_t)(k0 + ty + j) * N2 + (n0 + tx)];
    __syncthreads();
#pragma unroll
    for (int j = 0; j < 32; j += 8)
      outp[(size_t)(n0 + ty + j) * K2 + (k0 + tx)] = f2bf(tile[tx * 33 + (ty + j)]);
    return;
  }

  int lane = tid & 63;
  int wid = tid >> 6;
  int wy = wid >> 1, wx = wid & 1;

  const u16* A = A0;
  const u16* BT = BT0;
  void* Cout = C0;
  if (MODE == 5) {
    int z = blockIdx.z;
    A = A0 + (size_t)z * M * K;
    BT = BT0 + (size_t)z * N * K;
    Cout = (void*)((u16*)C0 + (size_t)z * M * N);
  }

  int bx = blockIdx.x, by = blockIdx.y;
  {
    int flat = by * gridDim.x + bx;
    int j = flat >> 3;
    by = (flat & 7) * 8 + (j & 7);
    bx = j >> 3;
  }
  int m0 = by * 128, n0 = bx * 128;

  bool isCr = false;
  if (MODE == 6) {
    isCr = (bx >= 32);
    A = isCr ? A1 : A0;
  }

  int rlo = lane & 15;
  int rr = tid >> 3;
  int cc = ((tid & 7) - rr) & 7;
  const u16* gA = A + (size_t)(m0 + rr) * K + cc * 8;
  const u16* gB = BT + (size_t)(n0 + rr) * K + cc * 8;
  u16* ldsA = lA + wid * 512;
  u16* ldsB = lB + wid * 512;
  size_t qstep = (size_t)32 * K;

  floatx4 acc[4][4];
#pragma unroll
  for (int mi = 0; mi < 4; mi++)
#pragma unroll
    for (int ni = 0; ni < 4; ni++)
#pragma unroll
      for (int e = 0; e < 4; e++) acc[mi][ni][e] = 0.0f;

  for (int kt = 0; kt < K; kt += 64) {
    __syncthreads();
#pragma unroll
    for (int q = 0; q < 4; q++) {
      __builtin_amdgcn_global_load_lds(gA + q * qstep + kt, ldsA + q * 2048, 16, 0, 0);
      __builtin_amdgcn_global_load_lds(gB + q * qstep + kt, ldsB + q * 2048, 16, 0, 0);
    }
    __syncthreads();
    short8 af[2][4], bfr[2][4];
#pragma unroll
    for (int s = 0; s < 2; s++) {
      int cbase = s * 4 + (lane >> 4);
#pragma unroll
      for (int mi = 0; mi < 4; mi++) {
        int row = wy * 64 + mi * 16 + rlo;
        af[s][mi] = *(const short8*)&lA[row * 64 + (((cbase + row) & 7) << 3)];
      }
#pragma unroll
      for (int ni = 0; ni < 4; ni++) {
        int row = wx * 64 + ni * 16 + rlo;
        bfr[s][ni] = *(const short8*)&lB[row * 64 + (((cbase + row) & 7) << 3)];
      }
    }
#pragma unroll
    for (int s = 0; s < 2; s++)
#pragma unroll
      for (int mi = 0; mi < 4; mi++)
#pragma unroll
        for (int ni = 0; ni < 4; ni++)
          acc[mi][ni] =
              __builtin_amdgcn_mfma_f32_16x16x32_bf16(af[s][mi], bfr[s][ni], acc[mi][ni], 0, 0, 0);
  }

  int rbase = (lane >> 4) * 4;
#pragma unroll
  for (int mi = 0; mi < 4; mi++) {
#pragma unroll
    for (int ni = 0; ni < 4; ni++) {
#pragma unroll
      for (int r = 0; r < 4; r++) {
        int row = m0 + wy * 64 + mi * 16 + rbase + r;
        int col = n0 + wx * 64 + ni * 16 + rlo;
        float v = acc[mi][ni][r];
        if (MODE == 6) {
          if (!isCr) {
            float tpos = fmaxf(v, 0.0f);
            ((u16*)C0)[(size_t)row * 4096 + col] = f2bf(tpos * tpos);
          } else {
            ((u16*)C1)[(size_t)row * 1024 + (col - 4096)] = f2bf(sigmoidf_(v));
          }
        } else if (MODE == 5) {
          ((u16*)Cout)[(size_t)row * N + col] = (blockIdx.z == 2) ? f2bf(sigmoidf_(v)) : f2bf(v);
        }
      }
    }
  }
}

// ---------------- bf16 MFMA GEMM 64x128 tile (full-fill variant for N=1024 GEMMs) ----------------
// grid (8, M/64) = 1024 blocks -> 4 blocks/CU (vs 512/2 for the 128-tile), doubling
// resident waves over the barrier drain. Same staging/swizzle pattern; A 2 rounds, B 4.
// Raster: 16-row slabs (gridDim.y==128).
// MODE 3: C0 fp32 = A0@B + R1;  MODE 4: C0 fp32 = R1 + bf2f(R2)*(A0@B)
template <int MODE>
__launch_bounds__(256, 4)
__global__ void gemm_bt64(const u16* __restrict__ A0, const u16* __restrict__ BT0,
                          const float* R1, const u16* R2,
                          void* C0, int M, int N, int K) {
  __shared__ u16 lA[64 * 64];
  __shared__ u16 lB[128 * 64];
  int tid = threadIdx.x;
  int lane = tid & 63;
  int wid = tid >> 6;   // wave -> n-quadrant: n = wid*32

  int bx = blockIdx.x, by = blockIdx.y;
  {
    int flat = by * gridDim.x + bx;   // gridDim.x == 8, gridDim.y == 128
    int j = flat >> 3;                // 0..127
    by = (flat & 7) * 16 + (j & 15);
    bx = j >> 4;
  }
  int m0 = by * 64, n0 = bx * 128;

  int rlo = lane & 15;
  int rr = tid >> 3;
  int cc = ((tid & 7) - rr) & 7;
  const u16* gA = A0 + (size_t)(m0 + rr) * K + cc * 8;
  const u16* gB = BT0 + (size_t)(n0 + rr) * K + cc * 8;
  u16* ldsA = lA + wid * 512;
  u16* ldsB = lB + wid * 512;
  size_t qstep = (size_t)32 * K;

  floatx4 acc[4][2];
#pragma unroll
  for (int mi = 0; mi < 4; mi++)
#pragma unroll
    for (int ni = 0; ni < 2; ni++)
#pragma unroll
      for (int e = 0; e < 4; e++) acc[mi][ni][e] = 0.0f;

  for (int kt = 0; kt < K; kt += 64) {
    __syncthreads();
#pragma unroll
    for (int q = 0; q < 2; q++)
      __builtin_amdgcn_global_load_lds(gA + q * qstep + kt, ldsA + q * 2048, 16, 0, 0);
#pragma unroll
    for (int q = 0; q < 4; q++)
      __builtin_amdgcn_global_load_lds(gB + q * qstep + kt, ldsB + q * 2048, 16, 0, 0);
    __syncthreads();
    short8 af[2][4], bfr[2][2];
#pragma unroll
    for (int s = 0; s < 2; s++) {
      int cbase = s * 4 + (lane >> 4);
#pragma unroll
      for (int mi = 0; mi < 4; mi++) {
        int row = mi * 16 + rlo;
        af[s][mi] = *(const short8*)&lA[row * 64 + (((cbase + row) & 7) << 3)];
      }
#pragma unroll
      for (int ni = 0; ni < 2; ni++) {
        int row = wid * 32 + ni * 16 + rlo;
        bfr[s][ni] = *(const short8*)&lB[row * 64 + (((cbase + row) & 7) << 3)];
      }
    }
#pragma unroll
    for (int s = 0; s < 2; s++)
#pragma unroll
      for (int mi = 0; mi < 4; mi++)
#pragma unroll
        for (int ni = 0; ni < 2; ni++)
          acc[mi][ni] =
              __builtin_amdgcn_mfma_f32_16x16x32_bf16(af[s][mi], bfr[s][ni], acc[mi][ni], 0, 0, 0);
  }

  int rbase = (lane >> 4) * 4;
#pragma unroll
  for (int mi = 0; mi < 4; mi++) {
#pragma unroll
    for (int ni = 0; ni < 2; ni++) {
#pragma unroll
      for (int r = 0; r < 4; r++) {
        int row = m0 + mi * 16 + rbase + r;
        int col = n0 + wid * 32 + ni * 16 + rlo;
        size_t idx = (size_t)row * N + col;
        float v = acc[mi][ni][r];
        if (MODE == 3) {
          ((float*)C0)[idx] = v + R1[idx];
        } else {
          ((float*)C0)[idx] = R1[idx] + bf2f(R2[idx]) * v;
        }
      }
    }
  }
}

extern "C" void kernel_launch(void* const* d_in, const int* in_sizes, int n_in,
                              void* d_out, int out_size, void* d_ws, size_t ws_size,
                              hipStream_t stream) {
  const float* x    = (const float*)d_in[0];
  const float* attx = (const float*)d_in[1];
  const float* aa0  = (const float*)d_in[2];
  const float* bb0  = (const float*)d_in[3];
  const float* pp0  = (const float*)d_in[4];
  const float* ffnx = (const float*)d_in[5];
  const float* ln1g = (const float*)d_in[6];
  const float* ln1b = (const float*)d_in[7];
  const float* ln2g = (const float*)d_in[8];
  const float* ln2b = (const float*)d_in[9];
  const float* mk   = (const float*)d_in[10];
  const float* mv   = (const float*)d_in[11];
  const float* mr   = (const float*)d_in[12];
  const float* decay= (const float*)d_in[13];
  const float* first= (const float*)d_in[14];
  const float* Wk   = (const float*)d_in[15];
  const float* Wv   = (const float*)d_in[16];
  const float* Wr   = (const float*)d_in[17];
  const float* Wo   = (const float*)d_in[18];
  const float* cmk  = (const float*)d_in[19];
  const float* cmr  = (const float*)d_in[20];
  const float* Ck   = (const float*)d_in[21];
  const float* Cr   = (const float*)d_in[22];
  const float* Cv   = (const float*)d_in[23];

  float* out      = (float*)d_out;
  float* xn_last  = out + (size_t)BB * TT * DD;
  float* aa_out   = xn_last + BB * DD;
  float* bb_out   = aa_out + BB * DD;
  float* pp_out   = bb_out + BB * DD;
  float* xn2_last = pp_out + BB * DD;
  float* x1 = out;  // x1 lives in the out buffer

  char* ws = (char*)d_ws;
  const size_t MB = 1024ull * 1024ull;
  u16* WT4   = (u16*)(ws + 0 * MB);     // Wk,Wv,Wr,Wo transposed bf16, 2MB each
  u16* WkT   = WT4;
  u16* WoT   = WT4 + 3u * 1024 * 1024;
  u16* CkCrT = (u16*)(ws + 8 * MB);     // [5120,1024] bf16 = 10MB
  u16* CrTd  = CkCrT + (size_t)4096 * 1024;
  u16* CvT   = (u16*)(ws + 18 * MB);    // 8MB  [1024,4096]
  u16* xk    = (u16*)(ws + 26 * MB);    // 16MB each, contiguous for batched QKV A
  u16* xv    = (u16*)(ws + 42 * MB);
  u16* xr    = (u16*)(ws + 58 * MB);
  u16* kbuf  = (u16*)(ws + 74 * MB);    // 16MB bf16 each, contiguous for batched QKV C
  u16* vbuf  = (u16*)(ws + 90 * MB);
  u16* sigr  = (u16*)(ws + 106 * MB);
  float* sab = (float*)(ws + 122 * MB); // 1MB each
  float* sbb = (float*)(ws + 123 * MB);
  float* psb = (float*)(ws + 124 * MB);
  // reuse (lifetimes disjoint):
  u16* rmb   = (u16*)(ws + 26 * MB);    // over xk (dead after QKV GEMM)
  u16* xk2   = (u16*)(ws + 26 * MB);    // over rmb (dead after Wo GEMM)
  u16* xr2   = (u16*)(ws + 42 * MB);    // over xv
  u16* sigr2 = (u16*)(ws + 58 * MB);    // over xr
  u16* kc    = (u16*)(ws + 74 * MB);    // 64MB over kbuf/vbuf/sigr/s* (dead after wkv)

  // prologue: ln1mix (8192) + Wk/Wv/Wr transposes (3072)
  prologue_kernel<<<MM + 3072, 256, 0, stream>>>(
      x, attx, ln1g, ln1b, mk, mv, mr, xk, xv, xr, xn_last, Wk, Wv, Wr, WT4);

  // batched QKV (z<3) + Wo/Cr/Ck/Cv transpose backfill (z=3..22)
  gemm_bt<5><<<dim3(8, 64, 23), 256, 0, stream>>>(
      xk, nullptr, WkT, kbuf, nullptr, MM, 1024, 1024,
      Wo, Cr, Ck, Cv, WoT, CrTd, CkCrT, CvT);

  wkv_chunk_sum<<<NCHAN * NCH / 256, 256, 0, stream>>>(kbuf, vbuf, decay, sab, sbb, psb);
  wkv_scan_out<<<NCHAN * NCH / 256, 256, 0, stream>>>(kbuf, vbuf, sigr, decay, first,
                                                      aa0, bb0, pp0, sab, sbb, psb, rmb,
                                                      aa_out, bb_out, pp_out);

  // Wo GEMM (64-row tile, 1024 blocks -> full fill): x1 = rmb@Wo + x
  gemm_bt64<3><<<dim3(8, 128), 256, 0, stream>>>(rmb, WoT, x, nullptr, x1, MM, 1024, 1024);

  ln2mix_kernel<<<MM, 256, 0, stream>>>(x1, ffnx, ln2g, ln2b, cmk, cmr, xk2, xr2, xn2_last);

  // merged FFN [Ck|Cr]
  gemm_bt<6><<<dim3(40, 64), 256, 0, stream>>>(xk2, xr2, CkCrT, kc, sigr2, MM, 5120, 1024,
                                               nullptr, nullptr, nullptr, nullptr,
                                               nullptr, nullptr, nullptr, nullptr);

  // Cv GEMM (64-row tile, full fill): out = x1 + sigr2 * (kc@Cv)
  gemm_bt64<4><<<dim3(8, 128), 256, 0, stream>>>(kc, CvT, x1, sigr2, out, MM, 1024, 4096);
}